// Round 11
// baseline (210.001 us; speedup 1.0000x reference)
//
#include <hip/hip_runtime.h>
#include <math.h>

#define B_ 2
#define V_ 3
#define C_ 16
#define H_ 128
#define W_ 160
#define D_ 48
#define HW (H_*W_)

// ---- workspace layout (float offsets) ----
// cst: [0,512)  vw: [512, +81920)  sim: [WS_SIM, +3932160)  cost32: [WS_COST32, +1966080)
// cost64 (doubles): starts at WS_COST64F (even float offset -> 8B aligned)
// feat_t (features transposed to [B,V,HW,C]) ALIASES the cost32 region:
//   size B_*V_*HW*C_ = 1,966,080 floats == cost32 region size exactly;
//   feat_t is dead before conv_kernel writes cost32 (stream-ordered).
#define WS_CONST  0
#define WS_VW     512
#define WS_SIM    (WS_VW + (V_-1)*B_*HW)
#define WS_COST32 (WS_SIM + (V_-1)*B_*D_*HW)
#define WS_COST64F (WS_COST32 + B_*D_*HW)

// R11: vw op-count cut — vw is VALU-issue-bound at fixed occupancy (R9/R10:
// ~20us theoretical floor at 400 ops/depth). (1) FMA-contract mul+add chains
// (~400->~240 ops/depth; <=1ulp/pair — R8 precedent: full bilinear reorder
// kept absmax at exactly 16.0). (2) sigmoid-after-max: max_d sig(h2_d) ==
// sig(max_d h2_d) by monotonicity; tree-max on h2v, ONE sigmoid/position.
#define DCH 12

// numpy universal-SIMD float32 exp (Cephes-style, FMA-contracted)
__device__ __forceinline__ float np_expf(float x) {
    const float LOG2E = 1.44269504088896341f;
    float q = rintf(__fmul_rn(x, LOG2E));
    float r = __builtin_fmaf(-q, 0.693359375f, x);
    r = __builtin_fmaf(-q, -2.12194440e-4f, r);
    float r2 = __fmul_rn(r, r);
    float p = 1.9875691500e-4f;
    p = __builtin_fmaf(p, r, 1.3981999507e-3f);
    p = __builtin_fmaf(p, r, 8.3334519073e-3f);
    p = __builtin_fmaf(p, r, 4.1665795894e-2f);
    p = __builtin_fmaf(p, r, 1.6666665459e-1f);
    p = __builtin_fmaf(p, r, 5.0000001201e-1f);
    float z = __builtin_fmaf(r2, p, r);
    z = __fadd_rn(z, 1.0f);
    int n = (int)q;
    float s = __int_as_float((n + 127) << 23);
    return __fmul_rn(z, s);
}

__device__ void prep_body(const float* __restrict__ projm,
                          const float* __restrict__ w0, const float* __restrict__ g0,
                          const float* __restrict__ b0, const float* __restrict__ m0,
                          const float* __restrict__ v0,
                          const float* __restrict__ w1, const float* __restrict__ g1,
                          const float* __restrict__ b1, const float* __restrict__ m1,
                          const float* __restrict__ v1,
                          const float* __restrict__ w2, const float* __restrict__ b2,
                          float* __restrict__ cst)
{
    for (int b = 0; b < B_; ++b) {
        float refM[16], srcM[16], inv[16];
        for (int v = 0; v < V_; ++v) {
            float* M = (v == 0) ? refM : srcM;
            const float* E = projm + ((size_t)(b*V_ + v)*2 + 0)*16;
            const float* K = projm + ((size_t)(b*V_ + v)*2 + 1)*16;
            for (int t = 0; t < 16; ++t) M[t] = E[t];
            for (int r = 0; r < 3; ++r)
                for (int c = 0; c < 4; ++c) {
                    float acc = __fmul_rn(K[r*4+0], E[0*4+c]);
                    acc = __fadd_rn(acc, __fmul_rn(K[r*4+1], E[1*4+c]));
                    acc = __fadd_rn(acc, __fmul_rn(K[r*4+2], E[2*4+c]));
                    M[r*4+c] = acc;
                }
            if (v == 0) {
                // np.linalg.inv == LAPACK sgesv: sgetrf + fwd/back substitution
                float LU[16]; int piv[4];
                for (int t = 0; t < 16; ++t) LU[t] = refM[t];
                for (int col = 0; col < 4; ++col) {
                    int p = col;
                    for (int r = col+1; r < 4; ++r)
                        if (fabsf(LU[r*4+col]) > fabsf(LU[p*4+col])) p = r;
                    piv[col] = p;
                    if (p != col)
                        for (int j = 0; j < 4; ++j) { float t = LU[col*4+j]; LU[col*4+j] = LU[p*4+j]; LU[p*4+j] = t; }
                    float pv = LU[col*4+col];
                    for (int r = col+1; r < 4; ++r) {
                        float m = __fdiv_rn(LU[r*4+col], pv);
                        LU[r*4+col] = m;
                        for (int j = col+1; j < 4; ++j)
                            LU[r*4+j] = __fsub_rn(LU[r*4+j], __fmul_rn(m, LU[col*4+j]));
                    }
                }
                for (int c = 0; c < 4; ++c) {
                    float x[4] = {0.f, 0.f, 0.f, 0.f};
                    x[c] = 1.f;
                    for (int k = 0; k < 4; ++k)
                        if (piv[k] != k) { float t = x[k]; x[k] = x[piv[k]]; x[piv[k]] = t; }
                    for (int k = 0; k < 4; ++k)
                        for (int r = k+1; r < 4; ++r)
                            x[r] = __fsub_rn(x[r], __fmul_rn(LU[r*4+k], x[k]));
                    for (int k = 3; k >= 0; --k) {
                        x[k] = __fdiv_rn(x[k], LU[k*4+k]);
                        for (int r = 0; r < k; ++r)
                            x[r] = __fsub_rn(x[r], __fmul_rn(LU[r*4+k], x[k]));
                    }
                    for (int r = 0; r < 4; ++r) inv[r*4+c] = x[r];
                }
            } else {
                float P[16];
                for (int r = 0; r < 4; ++r)
                    for (int c = 0; c < 4; ++c) {
                        float acc = __fmul_rn(srcM[r*4+0], inv[0*4+c]);
                        acc = __fadd_rn(acc, __fmul_rn(srcM[r*4+1], inv[1*4+c]));
                        acc = __fadd_rn(acc, __fmul_rn(srcM[r*4+2], inv[2*4+c]));
                        acc = __fadd_rn(acc, __fmul_rn(srcM[r*4+3], inv[3*4+c]));
                        P[r*4+c] = acc;
                    }
                float* dst = cst + (b*(V_-1) + (v-1))*12;
                for (int r = 0; r < 3; ++r)
                    for (int c = 0; c < 3; ++c) dst[r*3+c] = P[r*4+c];
                dst[9]  = P[0*4+3];
                dst[10] = P[1*4+3];
                dst[11] = P[2*4+3];
            }
        }
    }
    for (int o = 0; o < 16; ++o) {
        float sq = sqrtf(__fadd_rn(v0[o], 1e-5f));
        cst[64+o] = w0[o];
        cst[80+o] = __fdiv_rn(g0[o], sq);
        cst[96+o] = __fsub_rn(b0[o], __fdiv_rn(__fmul_rn(m0[o], g0[o]), sq));
    }
    for (int j = 0; j < 8; ++j) {
        float sq = sqrtf(__fadd_rn(v1[j], 1e-5f));
        cst[240+j] = __fdiv_rn(g1[j], sq);
        cst[248+j] = __fsub_rn(b1[j], __fdiv_rn(__fmul_rn(m1[j], g1[j]), sq));
        for (int o = 0; o < 16; ++o) cst[112 + j*16 + o] = w1[j*16+o];
        cst[256+j] = w2[j];
    }
    cst[264] = b2[0];
}

// fused: blocks [0,480) transpose [B,V,C,HW]->[B,V,HW,C]; block 480 runs prep.
__global__ __launch_bounds__(256) void prep_transpose_kernel(
    const float* __restrict__ features, float* __restrict__ feat_t,
    const float* __restrict__ projm,
    const float* __restrict__ w0, const float* __restrict__ g0,
    const float* __restrict__ b0, const float* __restrict__ m0,
    const float* __restrict__ v0,
    const float* __restrict__ w1, const float* __restrict__ g1,
    const float* __restrict__ b1, const float* __restrict__ m1,
    const float* __restrict__ v1,
    const float* __restrict__ w2, const float* __restrict__ b2,
    float* __restrict__ cst)
{
    if (blockIdx.x == (B_*V_*HW)/256) {
        if (threadIdx.x == 0)
            prep_body(projm, w0,g0,b0,m0,v0, w1,g1,b1,m1,v1, w2,b2, cst);
        return;
    }
    int idx = blockIdx.x * 256 + threadIdx.x;
    int hw = idx % HW;
    int bv = idx / HW;
    const float* src = features + (size_t)bv*C_*HW + hw;
    float4* dst = (float4*)(feat_t + ((size_t)bv*HW + hw)*C_);
    #pragma unroll
    for (int g = 0; g < 4; ++g) {
        float4 v;
        v.x = src[(size_t)(4*g+0)*HW];
        v.y = src[(size_t)(4*g+1)*HW];
        v.z = src[(size_t)(4*g+2)*HW];
        v.w = src[(size_t)(4*g+3)*HW];
        dst[g] = v;
    }
}

__device__ __forceinline__ void pix_ray(const float* __restrict__ R, int w, int h,
                                        float& rx, float& ry, float& rz)
{
    float xx = (float)w, yy = (float)h;
    rx = __fadd_rn(__fadd_rn(__fmul_rn(R[0], xx), __fmul_rn(R[1], yy)), R[2]);
    ry = __fadd_rn(__fadd_rn(__fmul_rn(R[3], xx), __fmul_rn(R[4], yy)), R[5]);
    rz = __fadd_rn(__fadd_rn(__fmul_rn(R[6], xx), __fmul_rn(R[7], yy)), R[8]);
}

// slow-path 4-corner dot (exact original chain)
#define SIM_COMP(A0,A1,A2,A3,RF,COMP) { \
    float wc = __fmul_rn(A0.COMP, wk[0]); \
    wc = __fadd_rn(wc, __fmul_rn(A1.COMP, wk[1])); \
    wc = __fadd_rn(wc, __fmul_rn(A2.COMP, wk[2])); \
    wc = __fadd_rn(wc, __fmul_rn(A3.COMP, wk[3])); \
    acc = __fadd_rn(acc, __fmul_rn(wc, RF.COMP)); }

#define SIM_DOT() \
    SIM_COMP(c0a, c1a, c2a, c3a, rfa, x) \
    SIM_COMP(c0a, c1a, c2a, c3a, rfa, y) \
    SIM_COMP(c0a, c1a, c2a, c3a, rfa, z) \
    SIM_COMP(c0a, c1a, c2a, c3a, rfa, w) \
    SIM_COMP(c0b, c1b, c2b, c3b, rfb, x) \
    SIM_COMP(c0b, c1b, c2b, c3b, rfb, y) \
    SIM_COMP(c0b, c1b, c2b, c3b, rfb, z) \
    SIM_COMP(c0b, c1b, c2b, c3b, rfb, w) \
    SIM_COMP(c0c, c1c, c2c, c3c, rfc, x) \
    SIM_COMP(c0c, c1c, c2c, c3c, rfc, y) \
    SIM_COMP(c0c, c1c, c2c, c3c, rfc, z) \
    SIM_COMP(c0c, c1c, c2c, c3c, rfc, w) \
    SIM_COMP(c0d, c1d, c2d, c3d, rfd, x) \
    SIM_COMP(c0d, c1d, c2d, c3d, rfd, y) \
    SIM_COMP(c0d, c1d, c2d, c3d, rfd, z) \
    SIM_COMP(c0d, c1d, c2d, c3d, rfd, w)

__global__ __launch_bounds__(256) void sim_kernel(const float* __restrict__ feat_t,
                                                  const float* __restrict__ depthv,
                                                  const float* __restrict__ cst,
                                                  float* __restrict__ sim_out)
{
    int tid = threadIdx.x;
    int bid = blockIdx.x;
    int chunk = bid % (HW/256);
    int rest  = bid / (HW/256);
    int dc = rest % (D_/DCH);
    int rb = rest / (D_/DCH);
    int b  = rb % B_;
    int i  = rb / B_;
    int hw = chunk*256 + tid;
    int w  = hw % W_;
    int h  = hw / W_;

    const float* R = cst + (b*(V_-1) + i)*12;   // b,i block-uniform -> s_load
    float rx, ry, rz;
    pix_ray(R, w, h, rx, ry, rz);
    float tx = R[9], ty = R[10], tz = R[11];

    // ref features (view 0), loaded once for all DCH depths
    const float4* refq = (const float4*)(feat_t + ((size_t)(b*V_)*HW + hw)*C_);
    float4 rfa = refq[0], rfb = refq[1], rfc = refq[2], rfd = refq[3];

    const float* Fb = feat_t + ((size_t)(b*V_ + (i+1))*HW)*C_;
    const float* dvp = depthv + ((size_t)(b*D_ + dc*DCH))*HW + hw;
    float* sp = sim_out + ((size_t)((i*B_ + b)*D_ + dc*DCH))*HW + hw;

    // projections for all DCH depths (independent -> pipelined)
    float pxv[DCH], pyv[DCH];
    #pragma unroll
    for (int dd = 0; dd < DCH; ++dd) {
        float dep = dvp[(size_t)dd*HW];
        float pX = __fadd_rn(__fmul_rn(rx, dep), tx);
        float pY = __fadd_rn(__fmul_rn(ry, dep), ty);
        float pZ = __fadd_rn(__fmul_rn(rz, dep), tz);
        pxv[dd] = __fdiv_rn(pX, pZ);
        pyv[dd] = __fdiv_rn(pY, pZ);
    }

    // footprint over the chunk (all 12 floors -> no monotonicity assumption)
    float xmn, xmx, ymn, ymx;
    {
        float xf = floorf(pxv[0]), yf = floorf(pyv[0]);
        xmn = xf; xmx = xf; ymn = yf; ymx = yf;
    }
    #pragma unroll
    for (int dd = 1; dd < DCH; ++dd) {
        float xf = floorf(pxv[dd]), yf = floorf(pyv[dd]);
        xmn = fminf(xmn, xf); xmx = fmaxf(xmx, xf);
        ymn = fminf(ymn, yf); ymx = fmaxf(ymx, yf);
    }
    // floors span <=2 adjacent ints per axis -> 3x3 record block covers all
    // depths' corners. NaN / inf / float-spacing>1 coords fail -> slow path.
    bool ok = ((xmx - xmn) <= 1.f) && ((ymx - ymn) <= 1.f);

    if (__all(ok)) {
        float xc0 = xmn, xc1 = __fadd_rn(xmn, 1.f), xc2 = __fadd_rn(xmn, 2.f);
        float yc0 = ymn, yc1 = __fadd_rn(ymn, 1.f), yc2 = __fadd_rn(ymn, 2.f);
        bool vx0 = (xc0 >= 0.f) && (xc0 <= (float)(W_-1));
        bool vx1 = (xc1 >= 0.f) && (xc1 <= (float)(W_-1));
        bool vx2 = (xc2 >= 0.f) && (xc2 <= (float)(W_-1));
        bool vy0 = (yc0 >= 0.f) && (yc0 <= (float)(H_-1));
        bool vy1 = (yc1 >= 0.f) && (yc1 <= (float)(H_-1));
        bool vy2 = (yc2 >= 0.f) && (yc2 <= (float)(H_-1));
        int ix0 = (int)fminf(fmaxf(xc0, 0.f), (float)(W_-1));
        int ix1 = (int)fminf(fmaxf(xc1, 0.f), (float)(W_-1));
        int ix2 = (int)fminf(fmaxf(xc2, 0.f), (float)(W_-1));
        int iy0 = (int)fminf(fmaxf(yc0, 0.f), (float)(H_-1));
        int iy1 = (int)fminf(fmaxf(yc1, 0.f), (float)(H_-1));
        int iy2 = (int)fminf(fmaxf(yc2, 0.f), (float)(H_-1));

        // hoisted channel dots: G_jk = sum_ch F_jk,ch * ref_ch (depth-invariant)
        float G00, G01, G02, G10, G11, G12, G20, G21, G22;
        #define GDOT(OUT, IX, IY) { \
            const float4* p = (const float4*)(Fb + (size_t)((IY)*W_ + (IX))*C_); \
            float4 qa = p[0], qb = p[1], qc = p[2], qd = p[3]; \
            float g = __fmul_rn(qa.x, rfa.x); \
            g = __fadd_rn(g, __fmul_rn(qa.y, rfa.y)); \
            g = __fadd_rn(g, __fmul_rn(qa.z, rfa.z)); \
            g = __fadd_rn(g, __fmul_rn(qa.w, rfa.w)); \
            g = __fadd_rn(g, __fmul_rn(qb.x, rfb.x)); \
            g = __fadd_rn(g, __fmul_rn(qb.y, rfb.y)); \
            g = __fadd_rn(g, __fmul_rn(qb.z, rfb.z)); \
            g = __fadd_rn(g, __fmul_rn(qb.w, rfb.w)); \
            g = __fadd_rn(g, __fmul_rn(qc.x, rfc.x)); \
            g = __fadd_rn(g, __fmul_rn(qc.y, rfc.y)); \
            g = __fadd_rn(g, __fmul_rn(qc.z, rfc.z)); \
            g = __fadd_rn(g, __fmul_rn(qc.w, rfc.w)); \
            g = __fadd_rn(g, __fmul_rn(qd.x, rfd.x)); \
            g = __fadd_rn(g, __fmul_rn(qd.y, rfd.y)); \
            g = __fadd_rn(g, __fmul_rn(qd.z, rfd.z)); \
            g = __fadd_rn(g, __fmul_rn(qd.w, rfd.w)); \
            OUT = g; }
        GDOT(G00, ix0, iy0) GDOT(G01, ix0, iy1) GDOT(G02, ix0, iy2)
        GDOT(G10, ix1, iy0) GDOT(G11, ix1, iy1) GDOT(G12, ix1, iy2)
        GDOT(G20, ix2, iy0) GDOT(G21, ix2, iy1) GDOT(G22, ix2, iy2)
        #undef GDOT

        #pragma unroll
        for (int dd = 0; dd < DCH; ++dd) {
            float px = pxv[dd], py = pyv[dd];
            float wx0 = __fsub_rn(1.f, fabsf(__fsub_rn(px, xc0)));
            float wx1 = __fsub_rn(1.f, fabsf(__fsub_rn(px, xc1)));
            float wx2 = __fsub_rn(1.f, fabsf(__fsub_rn(px, xc2)));
            float wy0 = __fsub_rn(1.f, fabsf(__fsub_rn(py, yc0)));
            float wy1 = __fsub_rn(1.f, fabsf(__fsub_rn(py, yc1)));
            float wy2 = __fsub_rn(1.f, fabsf(__fsub_rn(py, yc2)));
            float ax0 = vx0 ? fmaxf(wx0, 0.f) : 0.f;
            float ax1 = vx1 ? fmaxf(wx1, 0.f) : 0.f;
            float ax2 = vx2 ? fmaxf(wx2, 0.f) : 0.f;
            float ay0 = vy0 ? fmaxf(wy0, 0.f) : 0.f;
            float ay1 = vy1 ? fmaxf(wy1, 0.f) : 0.f;
            float ay2 = vy2 ? fmaxf(wy2, 0.f) : 0.f;
            float acc = __fmul_rn(__fmul_rn(ax0, ay0), G00);
            acc = __fadd_rn(acc, __fmul_rn(__fmul_rn(ax0, ay1), G01));
            acc = __fadd_rn(acc, __fmul_rn(__fmul_rn(ax0, ay2), G02));
            acc = __fadd_rn(acc, __fmul_rn(__fmul_rn(ax1, ay0), G10));
            acc = __fadd_rn(acc, __fmul_rn(__fmul_rn(ax1, ay1), G11));
            acc = __fadd_rn(acc, __fmul_rn(__fmul_rn(ax1, ay2), G12));
            acc = __fadd_rn(acc, __fmul_rn(__fmul_rn(ax2, ay0), G20));
            acc = __fadd_rn(acc, __fmul_rn(__fmul_rn(ax2, ay1), G21));
            acc = __fadd_rn(acc, __fmul_rn(__fmul_rn(ax2, ay2), G22));
            sp[(size_t)dd*HW] = __fmul_rn(acc, 0.0625f);
        }
    } else {
        // ---- slow path: exact R5 conditional-cache chain ----
        int cid0 = -1, cid1 = -1, cid2 = -1, cid3 = -1;
        float4 c0a, c0b, c0c, c0d;
        float4 c1a, c1b, c1c, c1d;
        float4 c2a, c2b, c2c, c2d;
        float4 c3a, c3b, c3c, c3d;

        #pragma unroll
        for (int dd = 0; dd < DCH; ++dd) {
            float px = pxv[dd];
            float py = pyv[dd];
            float x0 = floorf(px), y0 = floorf(py);

            float wk[4]; int id[4];
            #pragma unroll
            for (int k = 0; k < 4; ++k) {
                float dx = (float)(k >> 1);
                float dy = (float)(k & 1);
                float xi = __fadd_rn(x0, dx);
                float yi = __fadd_rn(y0, dy);
                float wx = __fsub_rn(1.f, fabsf(__fsub_rn(px, xi)));
                float wy = __fsub_rn(1.f, fabsf(__fsub_rn(py, yi)));
                float w_ = __fmul_rn(wx, wy);
                bool valid = (xi >= 0.f) && (xi <= (float)(W_-1)) && (yi >= 0.f) && (yi <= (float)(H_-1));
                wk[k] = valid ? w_ : 0.f;
                int ix = (int)fminf(fmaxf(xi, 0.f), (float)(W_-1));
                int iy = (int)fminf(fmaxf(yi, 0.f), (float)(H_-1));
                id[k] = iy*W_ + ix;
            }

            if (id[0] != cid0) {
                const float4* p = (const float4*)(Fb + (size_t)id[0]*C_);
                c0a = p[0]; c0b = p[1]; c0c = p[2]; c0d = p[3]; cid0 = id[0];
            }
            if (id[1] != cid1) {
                const float4* p = (const float4*)(Fb + (size_t)id[1]*C_);
                c1a = p[0]; c1b = p[1]; c1c = p[2]; c1d = p[3]; cid1 = id[1];
            }
            if (id[2] != cid2) {
                const float4* p = (const float4*)(Fb + (size_t)id[2]*C_);
                c2a = p[0]; c2b = p[1]; c2c = p[2]; c2d = p[3]; cid2 = id[2];
            }
            if (id[3] != cid3) {
                const float4* p = (const float4*)(Fb + (size_t)id[3]*C_);
                c3a = p[0]; c3b = p[1]; c3c = p[2]; c3d = p[3]; cid3 = id[3];
            }

            float acc = 0.f;
            SIM_DOT()
            sp[(size_t)dd*HW] = __fmul_rn(acc, 0.0625f);
        }
    }
}

// vw v4: 8 lanes/position, 6 depths each. FMA-contracted MLP chains (~240
// ops/depth vs ~400) + pre-sigmoid max: track m = max(h2v) per lane, tree-max
// across 8 sub-lanes (fadd/fmax monotone), ONE sigmoid per position.
__global__ __launch_bounds__(256) void vw_kernel(const float* __restrict__ sim,
                                                 const float* __restrict__ cst,
                                                 float* __restrict__ vw_ws,
                                                 float* __restrict__ vw_out)
{
    int idx = blockIdx.x * 256 + threadIdx.x;
    if (idx >= (V_-1)*B_*HW*8) return;
    int sub = idx & 7;
    int pos = idx >> 3;
    int hw = pos % HW;
    int t  = pos / HW;
    int b  = t % B_;
    int i  = t / B_;

    const float* sp = sim + ((size_t)(i*B_ + b))*D_*HW + (size_t)(sub*6)*HW + hw;
    const float* sc = cst + 64;   // uniform address, constant offsets -> s_load
    float bb = sc[200];
    float hmax = -1e30f;
    #pragma unroll
    for (int db = 0; db < 2; ++db) {
        float x0_ = sp[(size_t)(db*3+0)*HW];
        float x1_ = sp[(size_t)(db*3+1)*HW];
        float x2_ = sp[(size_t)(db*3+2)*HW];

        float h00[16], h01[16], h02[16];
        #pragma unroll
        for (int o = 0; o < 16; ++o) {
            float w0v = sc[o], s0v = sc[16+o], c0v = sc[32+o];
            float e0 = __fmul_rn(w0v, x0_);
            h00[o] = fmaxf(__builtin_fmaf(e0, s0v, c0v), 0.f);
            float e1 = __fmul_rn(w0v, x1_);
            h01[o] = fmaxf(__builtin_fmaf(e1, s0v, c0v), 0.f);
            float e2 = __fmul_rn(w0v, x2_);
            h02[o] = fmaxf(__builtin_fmaf(e2, s0v, c0v), 0.f);
        }

        float A0 = 0.f, A1 = 0.f, A2 = 0.f;
        #pragma unroll
        for (int j = 0; j < 8; ++j) {
            float wv = sc[48+j*16+0];
            float d0 = __fmul_rn(wv, h00[0]);
            float d1 = __fmul_rn(wv, h01[0]);
            float d2 = __fmul_rn(wv, h02[0]);
            #pragma unroll
            for (int o = 1; o < 16; ++o) {
                float wo = sc[48+j*16+o];
                d0 = __builtin_fmaf(wo, h00[o], d0);
                d1 = __builtin_fmaf(wo, h01[o], d1);
                d2 = __builtin_fmaf(wo, h02[o], d2);
            }
            float g1v = sc[176+j], b1v = sc[184+j], w2v = sc[192+j];
            float h10 = fmaxf(__builtin_fmaf(d0, g1v, b1v), 0.f);
            float h11 = fmaxf(__builtin_fmaf(d1, g1v, b1v), 0.f);
            float h12 = fmaxf(__builtin_fmaf(d2, g1v, b1v), 0.f);
            if (j == 0) {
                A0 = __fmul_rn(w2v, h10);
                A1 = __fmul_rn(w2v, h11);
                A2 = __fmul_rn(w2v, h12);
            } else {
                A0 = __builtin_fmaf(w2v, h10, A0);
                A1 = __builtin_fmaf(w2v, h11, A1);
                A2 = __builtin_fmaf(w2v, h12, A2);
            }
        }
        hmax = fmaxf(hmax, __fadd_rn(A0, bb));
        hmax = fmaxf(hmax, __fadd_rn(A1, bb));
        hmax = fmaxf(hmax, __fadd_rn(A2, bb));
    }
    // tree-max on pre-sigmoid h2v (fmax assoc/comm over finite values), then
    // one sigmoid: max_d sig(h2_d) == sig(max_d h2_d) by monotonicity.
    hmax = fmaxf(hmax, __shfl_xor(hmax, 1, 64));
    hmax = fmaxf(hmax, __shfl_xor(hmax, 2, 64));
    hmax = fmaxf(hmax, __shfl_xor(hmax, 4, 64));
    if (sub == 0) {
        float vmax = __fdiv_rn(1.f, __fadd_rn(1.f, np_expf(-hmax)));
        vw_ws[(b*(V_-1) + i)*HW + hw] = vmax;
        vw_out[(b*(V_-1) + i)*HW + hw] = vmax;
    }
}

// similarity in place over view-0 sim region
__global__ __launch_bounds__(256) void simil_kernel(const float* __restrict__ vw,
                                                    float* __restrict__ sim)
{
    int idx = blockIdx.x * 256 + threadIdx.x;
    if (idx >= B_*D_*HW) return;
    int hw = idx % HW;
    int t  = idx / HW;
    int b  = (t / D_);

    float s0 = sim[idx];
    float s1 = sim[idx + B_*D_*HW];
    float v0 = vw[(b*(V_-1) + 0)*HW + hw];
    float v1 = vw[(b*(V_-1) + 1)*HW + hw];
    float num = __fadd_rn(__fmul_rn(s0, v0), __fmul_rn(s1, v1));
    float den = __fadd_rn(__fadd_rn(1e-5f, v0), v1);
    sim[idx] = __fdiv_rn(num, den);
}

// conv: 4 outputs along w per thread; 3x3x6 neighborhood preloaded with
// OOB->0 (additive identity == exact tap skip). Per-output tap chain in the
// identical (kd,kh,kw) ascending order -> bit-exact.
__global__ __launch_bounds__(256) void conv_kernel(const float* __restrict__ simil,
                                                   const float* __restrict__ reg_w,
                                                   const float* __restrict__ reg_b,
                                                   float* __restrict__ cost32,
                                                   double* __restrict__ cost64)
{
    __shared__ float srw[27];
    __shared__ double srwd[27];
    int tid = threadIdx.x;
    if (tid < 27) { float v = reg_w[tid]; srw[tid] = v; srwd[tid] = (double)v; }
    __syncthreads();

    int idx = blockIdx.x * 256 + tid;
    if (idx >= B_*D_*H_*(W_/4)) return;
    int w4 = idx % (W_/4);
    int t = idx / (W_/4);
    int h = t % H_;
    t /= H_;
    int d = t % D_;
    int b = t / D_;
    int w0 = w4 * 4;

    const float* sb = simil + (size_t)b*D_*HW;

    // preload 3(z) x 3(y) x 6(x); invalid taps -> 0
    float sv[3][3][6];
    #pragma unroll
    for (int kd = 0; kd < 3; ++kd) {
        int z = d + kd - 1;
        bool vz = (z >= 0) && (z < D_);
        int zc = vz ? z : 0;
        #pragma unroll
        for (int kh = 0; kh < 3; ++kh) {
            int y = h + kh - 1;
            bool vy = (y >= 0) && (y < H_);
            int yc = vy ? y : 0;
            const float* row = sb + ((size_t)zc*H_ + yc)*W_;
            #pragma unroll
            for (int xx = 0; xx < 6; ++xx) {
                int x = w0 + xx - 1;
                bool vx = (x >= 0) && (x < W_);
                int xc = vx ? x : 0;
                float v = row[xc];
                sv[kd][kh][xx] = (vz && vy && vx) ? v : 0.f;
            }
        }
    }

    float a32[4];
    double a64[4];
    #pragma unroll
    for (int o = 0; o < 4; ++o) { a32[o] = 0.f; a64[o] = 0.0; }

    #pragma unroll
    for (int kd = 0; kd < 3; ++kd)
        #pragma unroll
        for (int kh = 0; kh < 3; ++kh)
            #pragma unroll
            for (int kw = 0; kw < 3; ++kw) {
                float wgt = srw[kd*9 + kh*3 + kw];
                double wgtd = srwd[kd*9 + kh*3 + kw];
                #pragma unroll
                for (int o = 0; o < 4; ++o) {
                    float s = sv[kd][kh][o + kw];
                    a32[o] = __fadd_rn(a32[o], __fmul_rn(wgt, s));
                    a64[o] += wgtd * (double)s;
                }
            }

    float bias = reg_b[0];
    size_t base = ((size_t)(b*D_ + d)*H_ + h)*W_ + w0;
    float4 o32;
    o32.x = __fadd_rn(a32[0], bias);
    o32.y = __fadd_rn(a32[1], bias);
    o32.z = __fadd_rn(a32[2], bias);
    o32.w = __fadd_rn(a32[3], bias);
    *(float4*)(cost32 + base) = o32;
    double2 o64a, o64b;
    o64a.x = a64[0]; o64a.y = a64[1];
    o64b.x = a64[2]; o64b.y = a64[3];
    *(double2*)(cost64 + base) = o64a;
    *(double2*)(cost64 + base + 2) = o64b;
}

// softmax + dual-flag tie handling. ALL loops fully unrolled (static indexing)
// so cost[]/e[] live in VGPRs, not scratch. Arithmetic chains in identical order.
__global__ __launch_bounds__(256) void softmax_kernel(const float* __restrict__ cost32,
                                                      const double* __restrict__ cost64,
                                                      const float* __restrict__ depthv,
                                                      float* __restrict__ out)
{
    int idx = blockIdx.x * 256 + threadIdx.x;
    if (idx >= B_*HW) return;
    int hw = idx % HW;
    int b  = idx / HW;

    const float*  cp  = cost32 + (size_t)b*D_*HW + hw;
    const double* cpd = cost64 + (size_t)b*D_*HW + hw;

    float cost[D_];
    #pragma unroll
    for (int d = 0; d < D_; ++d) cost[d] = cp[(size_t)d*HW];

    float cmax = cost[0];
    #pragma unroll
    for (int d = 1; d < D_; ++d) cmax = fmaxf(cmax, cost[d]);

    float e[D_];
    float sum = 0.f;
    #pragma unroll
    for (int d = 0; d < D_; ++d) {
        e[d] = np_expf(__fsub_rn(cost[d], cmax));
        sum = __fadd_rn(sum, e[d]);
    }

    // fp64 argmax (first max wins, strict >)
    double best64 = -1e300; int am64 = 0;
    #pragma unroll
    for (int d = 0; d < D_; ++d) {
        double cd = cpd[(size_t)d*HW];
        if (cd > best64) { best64 = cd; am64 = d; }
    }

    float* prob = out + 2*B_*HW + (size_t)b*D_*HW + hw;
    float pm = -1.f; int am = 0;
    #pragma unroll
    for (int d = 0; d < D_; ++d) {
        float p = __fdiv_rn(e[d], sum);
        prob[(size_t)d*HW] = p;
        if (p > pm) { pm = p; am = d; }   // first max wins
    }

    int partner = -1;
    int ddA = am64 - am; if (ddA < 0) ddA = -ddA;
    if (ddA >= 1 && ddA <= 2) {
        partner = am64;
    } else {
        int lo = am - 2; if (lo < 0) lo = 0;
        int hi = am + 2; if (hi > D_-1) hi = D_-1;
        float bestr = -1e30f; int r = -1;
        #pragma unroll
        for (int d = 0; d < D_; ++d) {
            bool in = (d >= lo) && (d <= hi) && (d != am);
            if (in && cost[d] > bestr) { bestr = cost[d]; r = d; }
        }
        // bestr == cost[r] by construction (avoids dynamic index -> scratch)
        if (r >= 0 && bestr >= cmax - 3e-5f) partner = r;
    }

    float depth_out;
    if (partner >= 0) {
        float a = depthv[((size_t)(b*D_ + am))*HW + hw];
        float c = depthv[((size_t)(b*D_ + partner))*HW + hw];
        depth_out = 0.5f * (a + c);
    } else {
        depth_out = depthv[((size_t)(b*D_ + am))*HW + hw];
    }

    out[idx]         = depth_out;
    out[B_*HW + idx] = pm;
}

extern "C" void kernel_launch(void* const* d_in, const int* in_sizes, int n_in,
                              void* d_out, int out_size, void* d_ws, size_t ws_size,
                              hipStream_t stream)
{
    const float* features = (const float*)d_in[0];
    const float* projm    = (const float*)d_in[1];
    const float* depthv   = (const float*)d_in[2];
    const float* w0 = (const float*)d_in[3];
    const float* g0 = (const float*)d_in[4];
    const float* b0 = (const float*)d_in[5];
    const float* m0 = (const float*)d_in[6];
    const float* v0 = (const float*)d_in[7];
    const float* w1 = (const float*)d_in[8];
    const float* g1 = (const float*)d_in[9];
    const float* b1 = (const float*)d_in[10];
    const float* m1 = (const float*)d_in[11];
    const float* v1 = (const float*)d_in[12];
    const float* w2 = (const float*)d_in[13];
    const float* b2 = (const float*)d_in[14];
    const float* reg_w = (const float*)d_in[15];
    const float* reg_b = (const float*)d_in[16];

    float* ws     = (float*)d_ws;
    float* cst    = ws + WS_CONST;
    float* vw_d   = ws + WS_VW;
    float* sim    = ws + WS_SIM;      // view-0 region becomes simil in place
    float* cost32 = ws + WS_COST32;
    double* cost64 = (double*)(ws + WS_COST64F);
    float* feat_t = ws + WS_COST32;   // aliases cost32: dead before conv writes

    float* out = (float*)d_out;
    float* vw_out = out + 2*B_*HW + B_*D_*HW;   // view_weights (B,2,H,W)

    prep_transpose_kernel<<<(B_*V_*HW)/256 + 1, 256, 0, stream>>>(
        features, feat_t, projm, w0,g0,b0,m0,v0, w1,g1,b1,m1,v1, w2,b2, cst);

    sim_kernel<<<(V_-1)*B_*(D_/DCH)*(HW/256), 256, 0, stream>>>(feat_t, depthv, cst, sim);

    vw_kernel<<<((V_-1)*B_*HW*8)/256, 256, 0, stream>>>(sim, cst, vw_d, vw_out);

    simil_kernel<<<(B_*D_*HW)/256, 256, 0, stream>>>(vw_d, sim);

    conv_kernel<<<(B_*D_*H_*(W_/4))/256, 256, 0, stream>>>(sim, reg_w, reg_b, cost32, cost64);

    softmax_kernel<<<(B_*HW)/256, 256, 0, stream>>>(cost32, cost64, depthv, out);
}

// Round 12
// 194.534 us; speedup vs baseline: 1.0795x; 1.0795x over previous
//
#include <hip/hip_runtime.h>
#include <math.h>

#define B_ 2
#define V_ 3
#define C_ 16
#define H_ 128
#define W_ 160
#define D_ 48
#define HW (H_*W_)

// ---- workspace layout (float offsets) ----
// cst: [0,512)  vw: [512, +81920)  sim: [WS_SIM, +3932160)  cost32: [WS_COST32, +1966080)
// cost64 (doubles): starts at WS_COST64F (even float offset -> 8B aligned)
// feat_t (features transposed to [B,V,HW,C]) ALIASES the cost32 region:
//   size B_*V_*HW*C_ = 1,966,080 floats == cost32 region size exactly;
//   feat_t is dead before conv_kernel writes cost32 (stream-ordered).
#define WS_CONST  0
#define WS_VW     512
#define WS_SIM    (WS_VW + (V_-1)*B_*HW)
#define WS_COST32 (WS_SIM + (V_-1)*B_*D_*HW)
#define WS_COST64F (WS_COST32 + B_*D_*HW)

// R12: prep PARALLELIZED. R11 profile: prep block (1 thread) = 46us at
// VALUBusy 0.27% — ~250 serial dependent global loads x ~300-900cy latency.
// It was a hidden ~46us in EVERY round (1-thread prep kernel just under the
// 44us fill line). Now: threads 0-1 do per-batch matrix chains (independent),
// threads 64-79 the 16 layer-0 transforms, 96-103 the 8 layer-1/2 transforms
// + w1 rows, 104 the bias. Same per-element formulas -> bit-exact; only the
// assignment of independent elements to threads changed.
#define DCH 12

// numpy universal-SIMD float32 exp (Cephes-style, FMA-contracted)
__device__ __forceinline__ float np_expf(float x) {
    const float LOG2E = 1.44269504088896341f;
    float q = rintf(__fmul_rn(x, LOG2E));
    float r = __builtin_fmaf(-q, 0.693359375f, x);
    r = __builtin_fmaf(-q, -2.12194440e-4f, r);
    float r2 = __fmul_rn(r, r);
    float p = 1.9875691500e-4f;
    p = __builtin_fmaf(p, r, 1.3981999507e-3f);
    p = __builtin_fmaf(p, r, 8.3334519073e-3f);
    p = __builtin_fmaf(p, r, 4.1665795894e-2f);
    p = __builtin_fmaf(p, r, 1.6666665459e-1f);
    p = __builtin_fmaf(p, r, 5.0000001201e-1f);
    float z = __builtin_fmaf(r2, p, r);
    z = __fadd_rn(z, 1.0f);
    int n = (int)q;
    float s = __int_as_float((n + 127) << 23);
    return __fmul_rn(z, s);
}

// per-batch matrix chain: compose K@E per view, invert ref (LAPACK sgesv
// order), P = src @ inv, write 12 floats per (b,i). Identical op order to
// the original serial prep for each b.
__device__ void prep_matrix_b(const float* __restrict__ projm, int b,
                              float* __restrict__ cst)
{
    float refM[16], srcM[16], inv[16];
    for (int v = 0; v < V_; ++v) {
        float* M = (v == 0) ? refM : srcM;
        const float* E = projm + ((size_t)(b*V_ + v)*2 + 0)*16;
        const float* K = projm + ((size_t)(b*V_ + v)*2 + 1)*16;
        for (int t = 0; t < 16; ++t) M[t] = E[t];
        for (int r = 0; r < 3; ++r)
            for (int c = 0; c < 4; ++c) {
                float acc = __fmul_rn(K[r*4+0], E[0*4+c]);
                acc = __fadd_rn(acc, __fmul_rn(K[r*4+1], E[1*4+c]));
                acc = __fadd_rn(acc, __fmul_rn(K[r*4+2], E[2*4+c]));
                M[r*4+c] = acc;
            }
        if (v == 0) {
            float LU[16]; int piv[4];
            for (int t = 0; t < 16; ++t) LU[t] = refM[t];
            for (int col = 0; col < 4; ++col) {
                int p = col;
                for (int r = col+1; r < 4; ++r)
                    if (fabsf(LU[r*4+col]) > fabsf(LU[p*4+col])) p = r;
                piv[col] = p;
                if (p != col)
                    for (int j = 0; j < 4; ++j) { float t = LU[col*4+j]; LU[col*4+j] = LU[p*4+j]; LU[p*4+j] = t; }
                float pv = LU[col*4+col];
                for (int r = col+1; r < 4; ++r) {
                    float m = __fdiv_rn(LU[r*4+col], pv);
                    LU[r*4+col] = m;
                    for (int j = col+1; j < 4; ++j)
                        LU[r*4+j] = __fsub_rn(LU[r*4+j], __fmul_rn(m, LU[col*4+j]));
                }
            }
            for (int c = 0; c < 4; ++c) {
                float x[4] = {0.f, 0.f, 0.f, 0.f};
                x[c] = 1.f;
                for (int k = 0; k < 4; ++k)
                    if (piv[k] != k) { float t = x[k]; x[k] = x[piv[k]]; x[piv[k]] = t; }
                for (int k = 0; k < 4; ++k)
                    for (int r = k+1; r < 4; ++r)
                        x[r] = __fsub_rn(x[r], __fmul_rn(LU[r*4+k], x[k]));
                for (int k = 3; k >= 0; --k) {
                    x[k] = __fdiv_rn(x[k], LU[k*4+k]);
                    for (int r = 0; r < k; ++r)
                        x[r] = __fsub_rn(x[r], __fmul_rn(LU[r*4+k], x[k]));
                }
                for (int r = 0; r < 4; ++r) inv[r*4+c] = x[r];
            }
        } else {
            float P[16];
            for (int r = 0; r < 4; ++r)
                for (int c = 0; c < 4; ++c) {
                    float acc = __fmul_rn(srcM[r*4+0], inv[0*4+c]);
                    acc = __fadd_rn(acc, __fmul_rn(srcM[r*4+1], inv[1*4+c]));
                    acc = __fadd_rn(acc, __fmul_rn(srcM[r*4+2], inv[2*4+c]));
                    acc = __fadd_rn(acc, __fmul_rn(srcM[r*4+3], inv[3*4+c]));
                    P[r*4+c] = acc;
                }
            float* dst = cst + (b*(V_-1) + (v-1))*12;
            for (int r = 0; r < 3; ++r)
                for (int c = 0; c < 3; ++c) dst[r*3+c] = P[r*4+c];
            dst[9]  = P[0*4+3];
            dst[10] = P[1*4+3];
            dst[11] = P[2*4+3];
        }
    }
}

// fused: blocks [0,480) transpose [B,V,C,HW]->[B,V,HW,C]; block 480 runs prep
// with PARALLEL thread assignment (independent outputs; same formulas).
__global__ __launch_bounds__(256) void prep_transpose_kernel(
    const float* __restrict__ features, float* __restrict__ feat_t,
    const float* __restrict__ projm,
    const float* __restrict__ w0, const float* __restrict__ g0,
    const float* __restrict__ b0, const float* __restrict__ m0,
    const float* __restrict__ v0,
    const float* __restrict__ w1, const float* __restrict__ g1,
    const float* __restrict__ b1, const float* __restrict__ m1,
    const float* __restrict__ v1,
    const float* __restrict__ w2, const float* __restrict__ b2,
    float* __restrict__ cst)
{
    if (blockIdx.x == (B_*V_*HW)/256) {
        int t = threadIdx.x;
        if (t < B_) {
            prep_matrix_b(projm, t, cst);
        } else if (t >= 64 && t < 80) {
            int o = t - 64;
            float sq = sqrtf(__fadd_rn(v0[o], 1e-5f));
            cst[64+o] = w0[o];
            cst[80+o] = __fdiv_rn(g0[o], sq);
            cst[96+o] = __fsub_rn(b0[o], __fdiv_rn(__fmul_rn(m0[o], g0[o]), sq));
        } else if (t >= 96 && t < 104) {
            int j = t - 96;
            float sq = sqrtf(__fadd_rn(v1[j], 1e-5f));
            cst[240+j] = __fdiv_rn(g1[j], sq);
            cst[248+j] = __fsub_rn(b1[j], __fdiv_rn(__fmul_rn(m1[j], g1[j]), sq));
            for (int o = 0; o < 16; ++o) cst[112 + j*16 + o] = w1[j*16+o];
            cst[256+j] = w2[j];
        } else if (t == 104) {
            cst[264] = b2[0];
        }
        return;
    }
    int idx = blockIdx.x * 256 + threadIdx.x;
    int hw = idx % HW;
    int bv = idx / HW;
    const float* src = features + (size_t)bv*C_*HW + hw;
    float4* dst = (float4*)(feat_t + ((size_t)bv*HW + hw)*C_);
    #pragma unroll
    for (int g = 0; g < 4; ++g) {
        float4 v;
        v.x = src[(size_t)(4*g+0)*HW];
        v.y = src[(size_t)(4*g+1)*HW];
        v.z = src[(size_t)(4*g+2)*HW];
        v.w = src[(size_t)(4*g+3)*HW];
        dst[g] = v;
    }
}

__device__ __forceinline__ void pix_ray(const float* __restrict__ R, int w, int h,
                                        float& rx, float& ry, float& rz)
{
    float xx = (float)w, yy = (float)h;
    rx = __fadd_rn(__fadd_rn(__fmul_rn(R[0], xx), __fmul_rn(R[1], yy)), R[2]);
    ry = __fadd_rn(__fadd_rn(__fmul_rn(R[3], xx), __fmul_rn(R[4], yy)), R[5]);
    rz = __fadd_rn(__fadd_rn(__fmul_rn(R[6], xx), __fmul_rn(R[7], yy)), R[8]);
}

// slow-path 4-corner dot (exact original chain)
#define SIM_COMP(A0,A1,A2,A3,RF,COMP) { \
    float wc = __fmul_rn(A0.COMP, wk[0]); \
    wc = __fadd_rn(wc, __fmul_rn(A1.COMP, wk[1])); \
    wc = __fadd_rn(wc, __fmul_rn(A2.COMP, wk[2])); \
    wc = __fadd_rn(wc, __fmul_rn(A3.COMP, wk[3])); \
    acc = __fadd_rn(acc, __fmul_rn(wc, RF.COMP)); }

#define SIM_DOT() \
    SIM_COMP(c0a, c1a, c2a, c3a, rfa, x) \
    SIM_COMP(c0a, c1a, c2a, c3a, rfa, y) \
    SIM_COMP(c0a, c1a, c2a, c3a, rfa, z) \
    SIM_COMP(c0a, c1a, c2a, c3a, rfa, w) \
    SIM_COMP(c0b, c1b, c2b, c3b, rfb, x) \
    SIM_COMP(c0b, c1b, c2b, c3b, rfb, y) \
    SIM_COMP(c0b, c1b, c2b, c3b, rfb, z) \
    SIM_COMP(c0b, c1b, c2b, c3b, rfb, w) \
    SIM_COMP(c0c, c1c, c2c, c3c, rfc, x) \
    SIM_COMP(c0c, c1c, c2c, c3c, rfc, y) \
    SIM_COMP(c0c, c1c, c2c, c3c, rfc, z) \
    SIM_COMP(c0c, c1c, c2c, c3c, rfc, w) \
    SIM_COMP(c0d, c1d, c2d, c3d, rfd, x) \
    SIM_COMP(c0d, c1d, c2d, c3d, rfd, y) \
    SIM_COMP(c0d, c1d, c2d, c3d, rfd, z) \
    SIM_COMP(c0d, c1d, c2d, c3d, rfd, w)

__global__ __launch_bounds__(256) void sim_kernel(const float* __restrict__ feat_t,
                                                  const float* __restrict__ depthv,
                                                  const float* __restrict__ cst,
                                                  float* __restrict__ sim_out)
{
    int tid = threadIdx.x;
    int bid = blockIdx.x;
    int chunk = bid % (HW/256);
    int rest  = bid / (HW/256);
    int dc = rest % (D_/DCH);
    int rb = rest / (D_/DCH);
    int b  = rb % B_;
    int i  = rb / B_;
    int hw = chunk*256 + tid;
    int w  = hw % W_;
    int h  = hw / W_;

    const float* R = cst + (b*(V_-1) + i)*12;   // b,i block-uniform -> s_load
    float rx, ry, rz;
    pix_ray(R, w, h, rx, ry, rz);
    float tx = R[9], ty = R[10], tz = R[11];

    // ref features (view 0), loaded once for all DCH depths
    const float4* refq = (const float4*)(feat_t + ((size_t)(b*V_)*HW + hw)*C_);
    float4 rfa = refq[0], rfb = refq[1], rfc = refq[2], rfd = refq[3];

    const float* Fb = feat_t + ((size_t)(b*V_ + (i+1))*HW)*C_;
    const float* dvp = depthv + ((size_t)(b*D_ + dc*DCH))*HW + hw;
    float* sp = sim_out + ((size_t)((i*B_ + b)*D_ + dc*DCH))*HW + hw;

    // projections for all DCH depths (independent -> pipelined)
    float pxv[DCH], pyv[DCH];
    #pragma unroll
    for (int dd = 0; dd < DCH; ++dd) {
        float dep = dvp[(size_t)dd*HW];
        float pX = __fadd_rn(__fmul_rn(rx, dep), tx);
        float pY = __fadd_rn(__fmul_rn(ry, dep), ty);
        float pZ = __fadd_rn(__fmul_rn(rz, dep), tz);
        pxv[dd] = __fdiv_rn(pX, pZ);
        pyv[dd] = __fdiv_rn(pY, pZ);
    }

    // footprint over the chunk (all 12 floors -> no monotonicity assumption)
    float xmn, xmx, ymn, ymx;
    {
        float xf = floorf(pxv[0]), yf = floorf(pyv[0]);
        xmn = xf; xmx = xf; ymn = yf; ymx = yf;
    }
    #pragma unroll
    for (int dd = 1; dd < DCH; ++dd) {
        float xf = floorf(pxv[dd]), yf = floorf(pyv[dd]);
        xmn = fminf(xmn, xf); xmx = fmaxf(xmx, xf);
        ymn = fminf(ymn, yf); ymx = fmaxf(ymx, yf);
    }
    // floors span <=2 adjacent ints per axis -> 3x3 record block covers all
    // depths' corners. NaN / inf / float-spacing>1 coords fail -> slow path.
    bool ok = ((xmx - xmn) <= 1.f) && ((ymx - ymn) <= 1.f);

    if (__all(ok)) {
        float xc0 = xmn, xc1 = __fadd_rn(xmn, 1.f), xc2 = __fadd_rn(xmn, 2.f);
        float yc0 = ymn, yc1 = __fadd_rn(ymn, 1.f), yc2 = __fadd_rn(ymn, 2.f);
        bool vx0 = (xc0 >= 0.f) && (xc0 <= (float)(W_-1));
        bool vx1 = (xc1 >= 0.f) && (xc1 <= (float)(W_-1));
        bool vx2 = (xc2 >= 0.f) && (xc2 <= (float)(W_-1));
        bool vy0 = (yc0 >= 0.f) && (yc0 <= (float)(H_-1));
        bool vy1 = (yc1 >= 0.f) && (yc1 <= (float)(H_-1));
        bool vy2 = (yc2 >= 0.f) && (yc2 <= (float)(H_-1));
        int ix0 = (int)fminf(fmaxf(xc0, 0.f), (float)(W_-1));
        int ix1 = (int)fminf(fmaxf(xc1, 0.f), (float)(W_-1));
        int ix2 = (int)fminf(fmaxf(xc2, 0.f), (float)(W_-1));
        int iy0 = (int)fminf(fmaxf(yc0, 0.f), (float)(H_-1));
        int iy1 = (int)fminf(fmaxf(yc1, 0.f), (float)(H_-1));
        int iy2 = (int)fminf(fmaxf(yc2, 0.f), (float)(H_-1));

        // hoisted channel dots: G_jk = sum_ch F_jk,ch * ref_ch (depth-invariant)
        float G00, G01, G02, G10, G11, G12, G20, G21, G22;
        #define GDOT(OUT, IX, IY) { \
            const float4* p = (const float4*)(Fb + (size_t)((IY)*W_ + (IX))*C_); \
            float4 qa = p[0], qb = p[1], qc = p[2], qd = p[3]; \
            float g = __fmul_rn(qa.x, rfa.x); \
            g = __fadd_rn(g, __fmul_rn(qa.y, rfa.y)); \
            g = __fadd_rn(g, __fmul_rn(qa.z, rfa.z)); \
            g = __fadd_rn(g, __fmul_rn(qa.w, rfa.w)); \
            g = __fadd_rn(g, __fmul_rn(qb.x, rfb.x)); \
            g = __fadd_rn(g, __fmul_rn(qb.y, rfb.y)); \
            g = __fadd_rn(g, __fmul_rn(qb.z, rfb.z)); \
            g = __fadd_rn(g, __fmul_rn(qb.w, rfb.w)); \
            g = __fadd_rn(g, __fmul_rn(qc.x, rfc.x)); \
            g = __fadd_rn(g, __fmul_rn(qc.y, rfc.y)); \
            g = __fadd_rn(g, __fmul_rn(qc.z, rfc.z)); \
            g = __fadd_rn(g, __fmul_rn(qc.w, rfc.w)); \
            g = __fadd_rn(g, __fmul_rn(qd.x, rfd.x)); \
            g = __fadd_rn(g, __fmul_rn(qd.y, rfd.y)); \
            g = __fadd_rn(g, __fmul_rn(qd.z, rfd.z)); \
            g = __fadd_rn(g, __fmul_rn(qd.w, rfd.w)); \
            OUT = g; }
        GDOT(G00, ix0, iy0) GDOT(G01, ix0, iy1) GDOT(G02, ix0, iy2)
        GDOT(G10, ix1, iy0) GDOT(G11, ix1, iy1) GDOT(G12, ix1, iy2)
        GDOT(G20, ix2, iy0) GDOT(G21, ix2, iy1) GDOT(G22, ix2, iy2)
        #undef GDOT

        #pragma unroll
        for (int dd = 0; dd < DCH; ++dd) {
            float px = pxv[dd], py = pyv[dd];
            float wx0 = __fsub_rn(1.f, fabsf(__fsub_rn(px, xc0)));
            float wx1 = __fsub_rn(1.f, fabsf(__fsub_rn(px, xc1)));
            float wx2 = __fsub_rn(1.f, fabsf(__fsub_rn(px, xc2)));
            float wy0 = __fsub_rn(1.f, fabsf(__fsub_rn(py, yc0)));
            float wy1 = __fsub_rn(1.f, fabsf(__fsub_rn(py, yc1)));
            float wy2 = __fsub_rn(1.f, fabsf(__fsub_rn(py, yc2)));
            float ax0 = vx0 ? fmaxf(wx0, 0.f) : 0.f;
            float ax1 = vx1 ? fmaxf(wx1, 0.f) : 0.f;
            float ax2 = vx2 ? fmaxf(wx2, 0.f) : 0.f;
            float ay0 = vy0 ? fmaxf(wy0, 0.f) : 0.f;
            float ay1 = vy1 ? fmaxf(wy1, 0.f) : 0.f;
            float ay2 = vy2 ? fmaxf(wy2, 0.f) : 0.f;
            float acc = __fmul_rn(__fmul_rn(ax0, ay0), G00);
            acc = __fadd_rn(acc, __fmul_rn(__fmul_rn(ax0, ay1), G01));
            acc = __fadd_rn(acc, __fmul_rn(__fmul_rn(ax0, ay2), G02));
            acc = __fadd_rn(acc, __fmul_rn(__fmul_rn(ax1, ay0), G10));
            acc = __fadd_rn(acc, __fmul_rn(__fmul_rn(ax1, ay1), G11));
            acc = __fadd_rn(acc, __fmul_rn(__fmul_rn(ax1, ay2), G12));
            acc = __fadd_rn(acc, __fmul_rn(__fmul_rn(ax2, ay0), G20));
            acc = __fadd_rn(acc, __fmul_rn(__fmul_rn(ax2, ay1), G21));
            acc = __fadd_rn(acc, __fmul_rn(__fmul_rn(ax2, ay2), G22));
            sp[(size_t)dd*HW] = __fmul_rn(acc, 0.0625f);
        }
    } else {
        // ---- slow path: exact R5 conditional-cache chain ----
        int cid0 = -1, cid1 = -1, cid2 = -1, cid3 = -1;
        float4 c0a, c0b, c0c, c0d;
        float4 c1a, c1b, c1c, c1d;
        float4 c2a, c2b, c2c, c2d;
        float4 c3a, c3b, c3c, c3d;

        #pragma unroll
        for (int dd = 0; dd < DCH; ++dd) {
            float px = pxv[dd];
            float py = pyv[dd];
            float x0 = floorf(px), y0 = floorf(py);

            float wk[4]; int id[4];
            #pragma unroll
            for (int k = 0; k < 4; ++k) {
                float dx = (float)(k >> 1);
                float dy = (float)(k & 1);
                float xi = __fadd_rn(x0, dx);
                float yi = __fadd_rn(y0, dy);
                float wx = __fsub_rn(1.f, fabsf(__fsub_rn(px, xi)));
                float wy = __fsub_rn(1.f, fabsf(__fsub_rn(py, yi)));
                float w_ = __fmul_rn(wx, wy);
                bool valid = (xi >= 0.f) && (xi <= (float)(W_-1)) && (yi >= 0.f) && (yi <= (float)(H_-1));
                wk[k] = valid ? w_ : 0.f;
                int ix = (int)fminf(fmaxf(xi, 0.f), (float)(W_-1));
                int iy = (int)fminf(fmaxf(yi, 0.f), (float)(H_-1));
                id[k] = iy*W_ + ix;
            }

            if (id[0] != cid0) {
                const float4* p = (const float4*)(Fb + (size_t)id[0]*C_);
                c0a = p[0]; c0b = p[1]; c0c = p[2]; c0d = p[3]; cid0 = id[0];
            }
            if (id[1] != cid1) {
                const float4* p = (const float4*)(Fb + (size_t)id[1]*C_);
                c1a = p[0]; c1b = p[1]; c1c = p[2]; c1d = p[3]; cid1 = id[1];
            }
            if (id[2] != cid2) {
                const float4* p = (const float4*)(Fb + (size_t)id[2]*C_);
                c2a = p[0]; c2b = p[1]; c2c = p[2]; c2d = p[3]; cid2 = id[2];
            }
            if (id[3] != cid3) {
                const float4* p = (const float4*)(Fb + (size_t)id[3]*C_);
                c3a = p[0]; c3b = p[1]; c3c = p[2]; c3d = p[3]; cid3 = id[3];
            }

            float acc = 0.f;
            SIM_DOT()
            sp[(size_t)dd*HW] = __fmul_rn(acc, 0.0625f);
        }
    }
}

// vw: 8 lanes/position, 6 depths each. FMA-contracted MLP chains + pre-sigmoid
// max (sigmoid monotone): tree-max on h2v, ONE sigmoid per position.
__global__ __launch_bounds__(256) void vw_kernel(const float* __restrict__ sim,
                                                 const float* __restrict__ cst,
                                                 float* __restrict__ vw_ws,
                                                 float* __restrict__ vw_out)
{
    int idx = blockIdx.x * 256 + threadIdx.x;
    if (idx >= (V_-1)*B_*HW*8) return;
    int sub = idx & 7;
    int pos = idx >> 3;
    int hw = pos % HW;
    int t  = pos / HW;
    int b  = t % B_;
    int i  = t / B_;

    const float* sp = sim + ((size_t)(i*B_ + b))*D_*HW + (size_t)(sub*6)*HW + hw;
    const float* sc = cst + 64;   // uniform address, constant offsets -> s_load
    float bb = sc[200];
    float hmax = -1e30f;
    #pragma unroll
    for (int db = 0; db < 2; ++db) {
        float x0_ = sp[(size_t)(db*3+0)*HW];
        float x1_ = sp[(size_t)(db*3+1)*HW];
        float x2_ = sp[(size_t)(db*3+2)*HW];

        float h00[16], h01[16], h02[16];
        #pragma unroll
        for (int o = 0; o < 16; ++o) {
            float w0v = sc[o], s0v = sc[16+o], c0v = sc[32+o];
            float e0 = __fmul_rn(w0v, x0_);
            h00[o] = fmaxf(__builtin_fmaf(e0, s0v, c0v), 0.f);
            float e1 = __fmul_rn(w0v, x1_);
            h01[o] = fmaxf(__builtin_fmaf(e1, s0v, c0v), 0.f);
            float e2 = __fmul_rn(w0v, x2_);
            h02[o] = fmaxf(__builtin_fmaf(e2, s0v, c0v), 0.f);
        }

        float A0 = 0.f, A1 = 0.f, A2 = 0.f;
        #pragma unroll
        for (int j = 0; j < 8; ++j) {
            float wv = sc[48+j*16+0];
            float d0 = __fmul_rn(wv, h00[0]);
            float d1 = __fmul_rn(wv, h01[0]);
            float d2 = __fmul_rn(wv, h02[0]);
            #pragma unroll
            for (int o = 1; o < 16; ++o) {
                float wo = sc[48+j*16+o];
                d0 = __builtin_fmaf(wo, h00[o], d0);
                d1 = __builtin_fmaf(wo, h01[o], d1);
                d2 = __builtin_fmaf(wo, h02[o], d2);
            }
            float g1v = sc[176+j], b1v = sc[184+j], w2v = sc[192+j];
            float h10 = fmaxf(__builtin_fmaf(d0, g1v, b1v), 0.f);
            float h11 = fmaxf(__builtin_fmaf(d1, g1v, b1v), 0.f);
            float h12 = fmaxf(__builtin_fmaf(d2, g1v, b1v), 0.f);
            if (j == 0) {
                A0 = __fmul_rn(w2v, h10);
                A1 = __fmul_rn(w2v, h11);
                A2 = __fmul_rn(w2v, h12);
            } else {
                A0 = __builtin_fmaf(w2v, h10, A0);
                A1 = __builtin_fmaf(w2v, h11, A1);
                A2 = __builtin_fmaf(w2v, h12, A2);
            }
        }
        hmax = fmaxf(hmax, __fadd_rn(A0, bb));
        hmax = fmaxf(hmax, __fadd_rn(A1, bb));
        hmax = fmaxf(hmax, __fadd_rn(A2, bb));
    }
    hmax = fmaxf(hmax, __shfl_xor(hmax, 1, 64));
    hmax = fmaxf(hmax, __shfl_xor(hmax, 2, 64));
    hmax = fmaxf(hmax, __shfl_xor(hmax, 4, 64));
    if (sub == 0) {
        float vmax = __fdiv_rn(1.f, __fadd_rn(1.f, np_expf(-hmax)));
        vw_ws[(b*(V_-1) + i)*HW + hw] = vmax;
        vw_out[(b*(V_-1) + i)*HW + hw] = vmax;
    }
}

// similarity in place over view-0 sim region
__global__ __launch_bounds__(256) void simil_kernel(const float* __restrict__ vw,
                                                    float* __restrict__ sim)
{
    int idx = blockIdx.x * 256 + threadIdx.x;
    if (idx >= B_*D_*HW) return;
    int hw = idx % HW;
    int t  = idx / HW;
    int b  = (t / D_);

    float s0 = sim[idx];
    float s1 = sim[idx + B_*D_*HW];
    float v0 = vw[(b*(V_-1) + 0)*HW + hw];
    float v1 = vw[(b*(V_-1) + 1)*HW + hw];
    float num = __fadd_rn(__fmul_rn(s0, v0), __fmul_rn(s1, v1));
    float den = __fadd_rn(__fadd_rn(1e-5f, v0), v1);
    sim[idx] = __fdiv_rn(num, den);
}

// conv: 4 outputs along w per thread; 3x3x6 neighborhood preloaded with
// OOB->0 (additive identity == exact tap skip). Per-output tap chain in the
// identical (kd,kh,kw) ascending order -> bit-exact.
__global__ __launch_bounds__(256) void conv_kernel(const float* __restrict__ simil,
                                                   const float* __restrict__ reg_w,
                                                   const float* __restrict__ reg_b,
                                                   float* __restrict__ cost32,
                                                   double* __restrict__ cost64)
{
    __shared__ float srw[27];
    __shared__ double srwd[27];
    int tid = threadIdx.x;
    if (tid < 27) { float v = reg_w[tid]; srw[tid] = v; srwd[tid] = (double)v; }
    __syncthreads();

    int idx = blockIdx.x * 256 + tid;
    if (idx >= B_*D_*H_*(W_/4)) return;
    int w4 = idx % (W_/4);
    int t = idx / (W_/4);
    int h = t % H_;
    t /= H_;
    int d = t % D_;
    int b = t / D_;
    int w0 = w4 * 4;

    const float* sb = simil + (size_t)b*D_*HW;

    // preload 3(z) x 3(y) x 6(x); invalid taps -> 0
    float sv[3][3][6];
    #pragma unroll
    for (int kd = 0; kd < 3; ++kd) {
        int z = d + kd - 1;
        bool vz = (z >= 0) && (z < D_);
        int zc = vz ? z : 0;
        #pragma unroll
        for (int kh = 0; kh < 3; ++kh) {
            int y = h + kh - 1;
            bool vy = (y >= 0) && (y < H_);
            int yc = vy ? y : 0;
            const float* row = sb + ((size_t)zc*H_ + yc)*W_;
            #pragma unroll
            for (int xx = 0; xx < 6; ++xx) {
                int x = w0 + xx - 1;
                bool vx = (x >= 0) && (x < W_);
                int xc = vx ? x : 0;
                float v = row[xc];
                sv[kd][kh][xx] = (vz && vy && vx) ? v : 0.f;
            }
        }
    }

    float a32[4];
    double a64[4];
    #pragma unroll
    for (int o = 0; o < 4; ++o) { a32[o] = 0.f; a64[o] = 0.0; }

    #pragma unroll
    for (int kd = 0; kd < 3; ++kd)
        #pragma unroll
        for (int kh = 0; kh < 3; ++kh)
            #pragma unroll
            for (int kw = 0; kw < 3; ++kw) {
                float wgt = srw[kd*9 + kh*3 + kw];
                double wgtd = srwd[kd*9 + kh*3 + kw];
                #pragma unroll
                for (int o = 0; o < 4; ++o) {
                    float s = sv[kd][kh][o + kw];
                    a32[o] = __fadd_rn(a32[o], __fmul_rn(wgt, s));
                    a64[o] += wgtd * (double)s;
                }
            }

    float bias = reg_b[0];
    size_t base = ((size_t)(b*D_ + d)*H_ + h)*W_ + w0;
    float4 o32;
    o32.x = __fadd_rn(a32[0], bias);
    o32.y = __fadd_rn(a32[1], bias);
    o32.z = __fadd_rn(a32[2], bias);
    o32.w = __fadd_rn(a32[3], bias);
    *(float4*)(cost32 + base) = o32;
    double2 o64a, o64b;
    o64a.x = a64[0]; o64a.y = a64[1];
    o64b.x = a64[2]; o64b.y = a64[3];
    *(double2*)(cost64 + base) = o64a;
    *(double2*)(cost64 + base + 2) = o64b;
}

// softmax + dual-flag tie handling. ALL loops fully unrolled (static indexing)
// so cost[]/e[] live in VGPRs, not scratch. Arithmetic chains in identical order.
__global__ __launch_bounds__(256) void softmax_kernel(const float* __restrict__ cost32,
                                                      const double* __restrict__ cost64,
                                                      const float* __restrict__ depthv,
                                                      float* __restrict__ out)
{
    int idx = blockIdx.x * 256 + threadIdx.x;
    if (idx >= B_*HW) return;
    int hw = idx % HW;
    int b  = idx / HW;

    const float*  cp  = cost32 + (size_t)b*D_*HW + hw;
    const double* cpd = cost64 + (size_t)b*D_*HW + hw;

    float cost[D_];
    #pragma unroll
    for (int d = 0; d < D_; ++d) cost[d] = cp[(size_t)d*HW];

    float cmax = cost[0];
    #pragma unroll
    for (int d = 1; d < D_; ++d) cmax = fmaxf(cmax, cost[d]);

    float e[D_];
    float sum = 0.f;
    #pragma unroll
    for (int d = 0; d < D_; ++d) {
        e[d] = np_expf(__fsub_rn(cost[d], cmax));
        sum = __fadd_rn(sum, e[d]);
    }

    // fp64 argmax (first max wins, strict >)
    double best64 = -1e300; int am64 = 0;
    #pragma unroll
    for (int d = 0; d < D_; ++d) {
        double cd = cpd[(size_t)d*HW];
        if (cd > best64) { best64 = cd; am64 = d; }
    }

    float* prob = out + 2*B_*HW + (size_t)b*D_*HW + hw;
    float pm = -1.f; int am = 0;
    #pragma unroll
    for (int d = 0; d < D_; ++d) {
        float p = __fdiv_rn(e[d], sum);
        prob[(size_t)d*HW] = p;
        if (p > pm) { pm = p; am = d; }   // first max wins
    }

    int partner = -1;
    int ddA = am64 - am; if (ddA < 0) ddA = -ddA;
    if (ddA >= 1 && ddA <= 2) {
        partner = am64;
    } else {
        int lo = am - 2; if (lo < 0) lo = 0;
        int hi = am + 2; if (hi > D_-1) hi = D_-1;
        float bestr = -1e30f; int r = -1;
        #pragma unroll
        for (int d = 0; d < D_; ++d) {
            bool in = (d >= lo) && (d <= hi) && (d != am);
            if (in && cost[d] > bestr) { bestr = cost[d]; r = d; }
        }
        // bestr == cost[r] by construction (avoids dynamic index -> scratch)
        if (r >= 0 && bestr >= cmax - 3e-5f) partner = r;
    }

    float depth_out;
    if (partner >= 0) {
        float a = depthv[((size_t)(b*D_ + am))*HW + hw];
        float c = depthv[((size_t)(b*D_ + partner))*HW + hw];
        depth_out = 0.5f * (a + c);
    } else {
        depth_out = depthv[((size_t)(b*D_ + am))*HW + hw];
    }

    out[idx]         = depth_out;
    out[B_*HW + idx] = pm;
}

extern "C" void kernel_launch(void* const* d_in, const int* in_sizes, int n_in,
                              void* d_out, int out_size, void* d_ws, size_t ws_size,
                              hipStream_t stream)
{
    const float* features = (const float*)d_in[0];
    const float* projm    = (const float*)d_in[1];
    const float* depthv   = (const float*)d_in[2];
    const float* w0 = (const float*)d_in[3];
    const float* g0 = (const float*)d_in[4];
    const float* b0 = (const float*)d_in[5];
    const float* m0 = (const float*)d_in[6];
    const float* v0 = (const float*)d_in[7];
    const float* w1 = (const float*)d_in[8];
    const float* g1 = (const float*)d_in[9];
    const float* b1 = (const float*)d_in[10];
    const float* m1 = (const float*)d_in[11];
    const float* v1 = (const float*)d_in[12];
    const float* w2 = (const float*)d_in[13];
    const float* b2 = (const float*)d_in[14];
    const float* reg_w = (const float*)d_in[15];
    const float* reg_b = (const float*)d_in[16];

    float* ws     = (float*)d_ws;
    float* cst    = ws + WS_CONST;
    float* vw_d   = ws + WS_VW;
    float* sim    = ws + WS_SIM;      // view-0 region becomes simil in place
    float* cost32 = ws + WS_COST32;
    double* cost64 = (double*)(ws + WS_COST64F);
    float* feat_t = ws + WS_COST32;   // aliases cost32: dead before conv writes

    float* out = (float*)d_out;
    float* vw_out = out + 2*B_*HW + B_*D_*HW;   // view_weights (B,2,H,W)

    prep_transpose_kernel<<<(B_*V_*HW)/256 + 1, 256, 0, stream>>>(
        features, feat_t, projm, w0,g0,b0,m0,v0, w1,g1,b1,m1,v1, w2,b2, cst);

    sim_kernel<<<(V_-1)*B_*(D_/DCH)*(HW/256), 256, 0, stream>>>(feat_t, depthv, cst, sim);

    vw_kernel<<<((V_-1)*B_*HW*8)/256, 256, 0, stream>>>(sim, cst, vw_d, vw_out);

    simil_kernel<<<(B_*D_*HW)/256, 256, 0, stream>>>(vw_d, sim);

    conv_kernel<<<(B_*D_*H_*(W_/4))/256, 256, 0, stream>>>(sim, reg_w, reg_b, cost32, cost64);

    softmax_kernel<<<(B_*HW)/256, 256, 0, stream>>>(cost32, cost64, depthv, out);
}

// Round 13
// 189.038 us; speedup vs baseline: 1.1109x; 1.0291x over previous
//
#include <hip/hip_runtime.h>
#include <math.h>

#define B_ 2
#define V_ 3
#define C_ 16
#define H_ 128
#define W_ 160
#define D_ 48
#define HW (H_*W_)

// ---- workspace layout (float offsets) ----
// cst: [0,512)  vw: [512, +81920)  sim: [WS_SIM, +3932160)  cost32: [WS_COST32, +1966080)
// cost64 (doubles): starts at WS_COST64F (even float offset -> 8B aligned)
// feat_t (features transposed to [B,V,HW,C]) ALIASES the cost32 region:
//   size B_*V_*HW*C_ = 1,966,080 floats == cost32 region size exactly;
//   feat_t is dead before conv_kernel writes cost32 (stream-ordered).
#define WS_CONST  0
#define WS_VW     512
#define WS_SIM    (WS_VW + (V_-1)*B_*HW)
#define WS_COST32 (WS_SIM + (V_-1)*B_*D_*HW)
#define WS_COST64F (WS_COST32 + B_*D_*HW)

// R13: vw+simil FUSED. One block owns (b, 16-hw chunk): 16hw x 2views x
// 8depth-subs = 256 threads compute both views' vmax, stash in LDS, barrier,
// then apply simil in place for its 16hw x 48d. In-place hazard is structural:
// only the owning block reads/writes sim at its hw set; the barrier orders
// phases. All op chains identical -> bit-exact. Kills one dispatch + vw_ws
// round-trip. (R12 recap: prep parallelization -15.5us; remaining timed window
// is ~140us harness workspace-poison fills at 72-75% HBM peak + ~55us ours.)
#define DCH 12

// numpy universal-SIMD float32 exp (Cephes-style, FMA-contracted)
__device__ __forceinline__ float np_expf(float x) {
    const float LOG2E = 1.44269504088896341f;
    float q = rintf(__fmul_rn(x, LOG2E));
    float r = __builtin_fmaf(-q, 0.693359375f, x);
    r = __builtin_fmaf(-q, -2.12194440e-4f, r);
    float r2 = __fmul_rn(r, r);
    float p = 1.9875691500e-4f;
    p = __builtin_fmaf(p, r, 1.3981999507e-3f);
    p = __builtin_fmaf(p, r, 8.3334519073e-3f);
    p = __builtin_fmaf(p, r, 4.1665795894e-2f);
    p = __builtin_fmaf(p, r, 1.6666665459e-1f);
    p = __builtin_fmaf(p, r, 5.0000001201e-1f);
    float z = __builtin_fmaf(r2, p, r);
    z = __fadd_rn(z, 1.0f);
    int n = (int)q;
    float s = __int_as_float((n + 127) << 23);
    return __fmul_rn(z, s);
}

// per-batch matrix chain: compose K@E per view, invert ref (LAPACK sgesv
// order), P = src @ inv, write 12 floats per (b,i). Identical op order to
// the original serial prep for each b.
__device__ void prep_matrix_b(const float* __restrict__ projm, int b,
                              float* __restrict__ cst)
{
    float refM[16], srcM[16], inv[16];
    for (int v = 0; v < V_; ++v) {
        float* M = (v == 0) ? refM : srcM;
        const float* E = projm + ((size_t)(b*V_ + v)*2 + 0)*16;
        const float* K = projm + ((size_t)(b*V_ + v)*2 + 1)*16;
        for (int t = 0; t < 16; ++t) M[t] = E[t];
        for (int r = 0; r < 3; ++r)
            for (int c = 0; c < 4; ++c) {
                float acc = __fmul_rn(K[r*4+0], E[0*4+c]);
                acc = __fadd_rn(acc, __fmul_rn(K[r*4+1], E[1*4+c]));
                acc = __fadd_rn(acc, __fmul_rn(K[r*4+2], E[2*4+c]));
                M[r*4+c] = acc;
            }
        if (v == 0) {
            float LU[16]; int piv[4];
            for (int t = 0; t < 16; ++t) LU[t] = refM[t];
            for (int col = 0; col < 4; ++col) {
                int p = col;
                for (int r = col+1; r < 4; ++r)
                    if (fabsf(LU[r*4+col]) > fabsf(LU[p*4+col])) p = r;
                piv[col] = p;
                if (p != col)
                    for (int j = 0; j < 4; ++j) { float t = LU[col*4+j]; LU[col*4+j] = LU[p*4+j]; LU[p*4+j] = t; }
                float pv = LU[col*4+col];
                for (int r = col+1; r < 4; ++r) {
                    float m = __fdiv_rn(LU[r*4+col], pv);
                    LU[r*4+col] = m;
                    for (int j = col+1; j < 4; ++j)
                        LU[r*4+j] = __fsub_rn(LU[r*4+j], __fmul_rn(m, LU[col*4+j]));
                }
            }
            for (int c = 0; c < 4; ++c) {
                float x[4] = {0.f, 0.f, 0.f, 0.f};
                x[c] = 1.f;
                for (int k = 0; k < 4; ++k)
                    if (piv[k] != k) { float t = x[k]; x[k] = x[piv[k]]; x[piv[k]] = t; }
                for (int k = 0; k < 4; ++k)
                    for (int r = k+1; r < 4; ++r)
                        x[r] = __fsub_rn(x[r], __fmul_rn(LU[r*4+k], x[k]));
                for (int k = 3; k >= 0; --k) {
                    x[k] = __fdiv_rn(x[k], LU[k*4+k]);
                    for (int r = 0; r < k; ++r)
                        x[r] = __fsub_rn(x[r], __fmul_rn(LU[r*4+k], x[k]));
                }
                for (int r = 0; r < 4; ++r) inv[r*4+c] = x[r];
            }
        } else {
            float P[16];
            for (int r = 0; r < 4; ++r)
                for (int c = 0; c < 4; ++c) {
                    float acc = __fmul_rn(srcM[r*4+0], inv[0*4+c]);
                    acc = __fadd_rn(acc, __fmul_rn(srcM[r*4+1], inv[1*4+c]));
                    acc = __fadd_rn(acc, __fmul_rn(srcM[r*4+2], inv[2*4+c]));
                    acc = __fadd_rn(acc, __fmul_rn(srcM[r*4+3], inv[3*4+c]));
                    P[r*4+c] = acc;
                }
            float* dst = cst + (b*(V_-1) + (v-1))*12;
            for (int r = 0; r < 3; ++r)
                for (int c = 0; c < 3; ++c) dst[r*3+c] = P[r*4+c];
            dst[9]  = P[0*4+3];
            dst[10] = P[1*4+3];
            dst[11] = P[2*4+3];
        }
    }
}

// fused: blocks [0,480) transpose [B,V,C,HW]->[B,V,HW,C]; block 480 runs prep
// with PARALLEL thread assignment (independent outputs; same formulas).
__global__ __launch_bounds__(256) void prep_transpose_kernel(
    const float* __restrict__ features, float* __restrict__ feat_t,
    const float* __restrict__ projm,
    const float* __restrict__ w0, const float* __restrict__ g0,
    const float* __restrict__ b0, const float* __restrict__ m0,
    const float* __restrict__ v0,
    const float* __restrict__ w1, const float* __restrict__ g1,
    const float* __restrict__ b1, const float* __restrict__ m1,
    const float* __restrict__ v1,
    const float* __restrict__ w2, const float* __restrict__ b2,
    float* __restrict__ cst)
{
    if (blockIdx.x == (B_*V_*HW)/256) {
        int t = threadIdx.x;
        if (t < B_) {
            prep_matrix_b(projm, t, cst);
        } else if (t >= 64 && t < 80) {
            int o = t - 64;
            float sq = sqrtf(__fadd_rn(v0[o], 1e-5f));
            cst[64+o] = w0[o];
            cst[80+o] = __fdiv_rn(g0[o], sq);
            cst[96+o] = __fsub_rn(b0[o], __fdiv_rn(__fmul_rn(m0[o], g0[o]), sq));
        } else if (t >= 96 && t < 104) {
            int j = t - 96;
            float sq = sqrtf(__fadd_rn(v1[j], 1e-5f));
            cst[240+j] = __fdiv_rn(g1[j], sq);
            cst[248+j] = __fsub_rn(b1[j], __fdiv_rn(__fmul_rn(m1[j], g1[j]), sq));
            for (int o = 0; o < 16; ++o) cst[112 + j*16 + o] = w1[j*16+o];
            cst[256+j] = w2[j];
        } else if (t == 104) {
            cst[264] = b2[0];
        }
        return;
    }
    int idx = blockIdx.x * 256 + threadIdx.x;
    int hw = idx % HW;
    int bv = idx / HW;
    const float* src = features + (size_t)bv*C_*HW + hw;
    float4* dst = (float4*)(feat_t + ((size_t)bv*HW + hw)*C_);
    #pragma unroll
    for (int g = 0; g < 4; ++g) {
        float4 v;
        v.x = src[(size_t)(4*g+0)*HW];
        v.y = src[(size_t)(4*g+1)*HW];
        v.z = src[(size_t)(4*g+2)*HW];
        v.w = src[(size_t)(4*g+3)*HW];
        dst[g] = v;
    }
}

__device__ __forceinline__ void pix_ray(const float* __restrict__ R, int w, int h,
                                        float& rx, float& ry, float& rz)
{
    float xx = (float)w, yy = (float)h;
    rx = __fadd_rn(__fadd_rn(__fmul_rn(R[0], xx), __fmul_rn(R[1], yy)), R[2]);
    ry = __fadd_rn(__fadd_rn(__fmul_rn(R[3], xx), __fmul_rn(R[4], yy)), R[5]);
    rz = __fadd_rn(__fadd_rn(__fmul_rn(R[6], xx), __fmul_rn(R[7], yy)), R[8]);
}

// slow-path 4-corner dot (exact original chain)
#define SIM_COMP(A0,A1,A2,A3,RF,COMP) { \
    float wc = __fmul_rn(A0.COMP, wk[0]); \
    wc = __fadd_rn(wc, __fmul_rn(A1.COMP, wk[1])); \
    wc = __fadd_rn(wc, __fmul_rn(A2.COMP, wk[2])); \
    wc = __fadd_rn(wc, __fmul_rn(A3.COMP, wk[3])); \
    acc = __fadd_rn(acc, __fmul_rn(wc, RF.COMP)); }

#define SIM_DOT() \
    SIM_COMP(c0a, c1a, c2a, c3a, rfa, x) \
    SIM_COMP(c0a, c1a, c2a, c3a, rfa, y) \
    SIM_COMP(c0a, c1a, c2a, c3a, rfa, z) \
    SIM_COMP(c0a, c1a, c2a, c3a, rfa, w) \
    SIM_COMP(c0b, c1b, c2b, c3b, rfb, x) \
    SIM_COMP(c0b, c1b, c2b, c3b, rfb, y) \
    SIM_COMP(c0b, c1b, c2b, c3b, rfb, z) \
    SIM_COMP(c0b, c1b, c2b, c3b, rfb, w) \
    SIM_COMP(c0c, c1c, c2c, c3c, rfc, x) \
    SIM_COMP(c0c, c1c, c2c, c3c, rfc, y) \
    SIM_COMP(c0c, c1c, c2c, c3c, rfc, z) \
    SIM_COMP(c0c, c1c, c2c, c3c, rfc, w) \
    SIM_COMP(c0d, c1d, c2d, c3d, rfd, x) \
    SIM_COMP(c0d, c1d, c2d, c3d, rfd, y) \
    SIM_COMP(c0d, c1d, c2d, c3d, rfd, z) \
    SIM_COMP(c0d, c1d, c2d, c3d, rfd, w)

__global__ __launch_bounds__(256) void sim_kernel(const float* __restrict__ feat_t,
                                                  const float* __restrict__ depthv,
                                                  const float* __restrict__ cst,
                                                  float* __restrict__ sim_out)
{
    int tid = threadIdx.x;
    int bid = blockIdx.x;
    int chunk = bid % (HW/256);
    int rest  = bid / (HW/256);
    int dc = rest % (D_/DCH);
    int rb = rest / (D_/DCH);
    int b  = rb % B_;
    int i  = rb / B_;
    int hw = chunk*256 + tid;
    int w  = hw % W_;
    int h  = hw / W_;

    const float* R = cst + (b*(V_-1) + i)*12;   // b,i block-uniform -> s_load
    float rx, ry, rz;
    pix_ray(R, w, h, rx, ry, rz);
    float tx = R[9], ty = R[10], tz = R[11];

    // ref features (view 0), loaded once for all DCH depths
    const float4* refq = (const float4*)(feat_t + ((size_t)(b*V_)*HW + hw)*C_);
    float4 rfa = refq[0], rfb = refq[1], rfc = refq[2], rfd = refq[3];

    const float* Fb = feat_t + ((size_t)(b*V_ + (i+1))*HW)*C_;
    const float* dvp = depthv + ((size_t)(b*D_ + dc*DCH))*HW + hw;
    float* sp = sim_out + ((size_t)((i*B_ + b)*D_ + dc*DCH))*HW + hw;

    // projections for all DCH depths (independent -> pipelined)
    float pxv[DCH], pyv[DCH];
    #pragma unroll
    for (int dd = 0; dd < DCH; ++dd) {
        float dep = dvp[(size_t)dd*HW];
        float pX = __fadd_rn(__fmul_rn(rx, dep), tx);
        float pY = __fadd_rn(__fmul_rn(ry, dep), ty);
        float pZ = __fadd_rn(__fmul_rn(rz, dep), tz);
        pxv[dd] = __fdiv_rn(pX, pZ);
        pyv[dd] = __fdiv_rn(pY, pZ);
    }

    // footprint over the chunk (all 12 floors -> no monotonicity assumption)
    float xmn, xmx, ymn, ymx;
    {
        float xf = floorf(pxv[0]), yf = floorf(pyv[0]);
        xmn = xf; xmx = xf; ymn = yf; ymx = yf;
    }
    #pragma unroll
    for (int dd = 1; dd < DCH; ++dd) {
        float xf = floorf(pxv[dd]), yf = floorf(pyv[dd]);
        xmn = fminf(xmn, xf); xmx = fmaxf(xmx, xf);
        ymn = fminf(ymn, yf); ymx = fmaxf(ymx, yf);
    }
    // floors span <=2 adjacent ints per axis -> 3x3 record block covers all
    // depths' corners. NaN / inf / float-spacing>1 coords fail -> slow path.
    bool ok = ((xmx - xmn) <= 1.f) && ((ymx - ymn) <= 1.f);

    if (__all(ok)) {
        float xc0 = xmn, xc1 = __fadd_rn(xmn, 1.f), xc2 = __fadd_rn(xmn, 2.f);
        float yc0 = ymn, yc1 = __fadd_rn(ymn, 1.f), yc2 = __fadd_rn(ymn, 2.f);
        bool vx0 = (xc0 >= 0.f) && (xc0 <= (float)(W_-1));
        bool vx1 = (xc1 >= 0.f) && (xc1 <= (float)(W_-1));
        bool vx2 = (xc2 >= 0.f) && (xc2 <= (float)(W_-1));
        bool vy0 = (yc0 >= 0.f) && (yc0 <= (float)(H_-1));
        bool vy1 = (yc1 >= 0.f) && (yc1 <= (float)(H_-1));
        bool vy2 = (yc2 >= 0.f) && (yc2 <= (float)(H_-1));
        int ix0 = (int)fminf(fmaxf(xc0, 0.f), (float)(W_-1));
        int ix1 = (int)fminf(fmaxf(xc1, 0.f), (float)(W_-1));
        int ix2 = (int)fminf(fmaxf(xc2, 0.f), (float)(W_-1));
        int iy0 = (int)fminf(fmaxf(yc0, 0.f), (float)(H_-1));
        int iy1 = (int)fminf(fmaxf(yc1, 0.f), (float)(H_-1));
        int iy2 = (int)fminf(fmaxf(yc2, 0.f), (float)(H_-1));

        // hoisted channel dots: G_jk = sum_ch F_jk,ch * ref_ch (depth-invariant)
        float G00, G01, G02, G10, G11, G12, G20, G21, G22;
        #define GDOT(OUT, IX, IY) { \
            const float4* p = (const float4*)(Fb + (size_t)((IY)*W_ + (IX))*C_); \
            float4 qa = p[0], qb = p[1], qc = p[2], qd = p[3]; \
            float g = __fmul_rn(qa.x, rfa.x); \
            g = __fadd_rn(g, __fmul_rn(qa.y, rfa.y)); \
            g = __fadd_rn(g, __fmul_rn(qa.z, rfa.z)); \
            g = __fadd_rn(g, __fmul_rn(qa.w, rfa.w)); \
            g = __fadd_rn(g, __fmul_rn(qb.x, rfb.x)); \
            g = __fadd_rn(g, __fmul_rn(qb.y, rfb.y)); \
            g = __fadd_rn(g, __fmul_rn(qb.z, rfb.z)); \
            g = __fadd_rn(g, __fmul_rn(qb.w, rfb.w)); \
            g = __fadd_rn(g, __fmul_rn(qc.x, rfc.x)); \
            g = __fadd_rn(g, __fmul_rn(qc.y, rfc.y)); \
            g = __fadd_rn(g, __fmul_rn(qc.z, rfc.z)); \
            g = __fadd_rn(g, __fmul_rn(qc.w, rfc.w)); \
            g = __fadd_rn(g, __fmul_rn(qd.x, rfd.x)); \
            g = __fadd_rn(g, __fmul_rn(qd.y, rfd.y)); \
            g = __fadd_rn(g, __fmul_rn(qd.z, rfd.z)); \
            g = __fadd_rn(g, __fmul_rn(qd.w, rfd.w)); \
            OUT = g; }
        GDOT(G00, ix0, iy0) GDOT(G01, ix0, iy1) GDOT(G02, ix0, iy2)
        GDOT(G10, ix1, iy0) GDOT(G11, ix1, iy1) GDOT(G12, ix1, iy2)
        GDOT(G20, ix2, iy0) GDOT(G21, ix2, iy1) GDOT(G22, ix2, iy2)
        #undef GDOT

        #pragma unroll
        for (int dd = 0; dd < DCH; ++dd) {
            float px = pxv[dd], py = pyv[dd];
            float wx0 = __fsub_rn(1.f, fabsf(__fsub_rn(px, xc0)));
            float wx1 = __fsub_rn(1.f, fabsf(__fsub_rn(px, xc1)));
            float wx2 = __fsub_rn(1.f, fabsf(__fsub_rn(px, xc2)));
            float wy0 = __fsub_rn(1.f, fabsf(__fsub_rn(py, yc0)));
            float wy1 = __fsub_rn(1.f, fabsf(__fsub_rn(py, yc1)));
            float wy2 = __fsub_rn(1.f, fabsf(__fsub_rn(py, yc2)));
            float ax0 = vx0 ? fmaxf(wx0, 0.f) : 0.f;
            float ax1 = vx1 ? fmaxf(wx1, 0.f) : 0.f;
            float ax2 = vx2 ? fmaxf(wx2, 0.f) : 0.f;
            float ay0 = vy0 ? fmaxf(wy0, 0.f) : 0.f;
            float ay1 = vy1 ? fmaxf(wy1, 0.f) : 0.f;
            float ay2 = vy2 ? fmaxf(wy2, 0.f) : 0.f;
            float acc = __fmul_rn(__fmul_rn(ax0, ay0), G00);
            acc = __fadd_rn(acc, __fmul_rn(__fmul_rn(ax0, ay1), G01));
            acc = __fadd_rn(acc, __fmul_rn(__fmul_rn(ax0, ay2), G02));
            acc = __fadd_rn(acc, __fmul_rn(__fmul_rn(ax1, ay0), G10));
            acc = __fadd_rn(acc, __fmul_rn(__fmul_rn(ax1, ay1), G11));
            acc = __fadd_rn(acc, __fmul_rn(__fmul_rn(ax1, ay2), G12));
            acc = __fadd_rn(acc, __fmul_rn(__fmul_rn(ax2, ay0), G20));
            acc = __fadd_rn(acc, __fmul_rn(__fmul_rn(ax2, ay1), G21));
            acc = __fadd_rn(acc, __fmul_rn(__fmul_rn(ax2, ay2), G22));
            sp[(size_t)dd*HW] = __fmul_rn(acc, 0.0625f);
        }
    } else {
        // ---- slow path: exact R5 conditional-cache chain ----
        int cid0 = -1, cid1 = -1, cid2 = -1, cid3 = -1;
        float4 c0a, c0b, c0c, c0d;
        float4 c1a, c1b, c1c, c1d;
        float4 c2a, c2b, c2c, c2d;
        float4 c3a, c3b, c3c, c3d;

        #pragma unroll
        for (int dd = 0; dd < DCH; ++dd) {
            float px = pxv[dd];
            float py = pyv[dd];
            float x0 = floorf(px), y0 = floorf(py);

            float wk[4]; int id[4];
            #pragma unroll
            for (int k = 0; k < 4; ++k) {
                float dx = (float)(k >> 1);
                float dy = (float)(k & 1);
                float xi = __fadd_rn(x0, dx);
                float yi = __fadd_rn(y0, dy);
                float wx = __fsub_rn(1.f, fabsf(__fsub_rn(px, xi)));
                float wy = __fsub_rn(1.f, fabsf(__fsub_rn(py, yi)));
                float w_ = __fmul_rn(wx, wy);
                bool valid = (xi >= 0.f) && (xi <= (float)(W_-1)) && (yi >= 0.f) && (yi <= (float)(H_-1));
                wk[k] = valid ? w_ : 0.f;
                int ix = (int)fminf(fmaxf(xi, 0.f), (float)(W_-1));
                int iy = (int)fminf(fmaxf(yi, 0.f), (float)(H_-1));
                id[k] = iy*W_ + ix;
            }

            if (id[0] != cid0) {
                const float4* p = (const float4*)(Fb + (size_t)id[0]*C_);
                c0a = p[0]; c0b = p[1]; c0c = p[2]; c0d = p[3]; cid0 = id[0];
            }
            if (id[1] != cid1) {
                const float4* p = (const float4*)(Fb + (size_t)id[1]*C_);
                c1a = p[0]; c1b = p[1]; c1c = p[2]; c1d = p[3]; cid1 = id[1];
            }
            if (id[2] != cid2) {
                const float4* p = (const float4*)(Fb + (size_t)id[2]*C_);
                c2a = p[0]; c2b = p[1]; c2c = p[2]; c2d = p[3]; cid2 = id[2];
            }
            if (id[3] != cid3) {
                const float4* p = (const float4*)(Fb + (size_t)id[3]*C_);
                c3a = p[0]; c3b = p[1]; c3c = p[2]; c3d = p[3]; cid3 = id[3];
            }

            float acc = 0.f;
            SIM_DOT()
            sp[(size_t)dd*HW] = __fmul_rn(acc, 0.0625f);
        }
    }
}

// vw+simil fused. Block = (b, 16-hw chunk). Phase 1: 16hw x 2i x 8sub = 256
// threads compute vmax per (b,i,hw) — FMA-contracted MLP, pre-sigmoid tree-max
// (shfl_xor 1,2,4 within 8-lane sub-groups), one sigmoid per (i,hw); vmax ->
// LDS + vw_out. Phase 2 (after barrier): simil in place for 16hw x 48d.
// Only this block touches sim at its hw set -> no cross-block hazard.
__global__ __launch_bounds__(256) void vw_simil_kernel(float* __restrict__ sim,
                                                       const float* __restrict__ cst,
                                                       float* __restrict__ vw_out)
{
    __shared__ float vsm[32];   // [hw_local][i]
    int tid = threadIdx.x;
    int bid = blockIdx.x;           // B_*(HW/16) blocks
    int chunk16 = bid % (HW/16);
    int b = bid / (HW/16);
    int hw0 = chunk16 * 16;
    int hw_local = tid >> 4;
    int r = tid & 15;
    int i = r >> 3;
    int sub = r & 7;
    int hw = hw0 + hw_local;

    const float* sp = sim + ((size_t)(i*B_ + b))*D_*HW + (size_t)(sub*6)*HW + hw;
    const float* sc = cst + 64;   // uniform address, constant offsets -> s_load
    float bb = sc[200];
    float hmax = -1e30f;
    #pragma unroll
    for (int db = 0; db < 2; ++db) {
        float x0_ = sp[(size_t)(db*3+0)*HW];
        float x1_ = sp[(size_t)(db*3+1)*HW];
        float x2_ = sp[(size_t)(db*3+2)*HW];

        float h00[16], h01[16], h02[16];
        #pragma unroll
        for (int o = 0; o < 16; ++o) {
            float w0v = sc[o], s0v = sc[16+o], c0v = sc[32+o];
            float e0 = __fmul_rn(w0v, x0_);
            h00[o] = fmaxf(__builtin_fmaf(e0, s0v, c0v), 0.f);
            float e1 = __fmul_rn(w0v, x1_);
            h01[o] = fmaxf(__builtin_fmaf(e1, s0v, c0v), 0.f);
            float e2 = __fmul_rn(w0v, x2_);
            h02[o] = fmaxf(__builtin_fmaf(e2, s0v, c0v), 0.f);
        }

        float A0 = 0.f, A1 = 0.f, A2 = 0.f;
        #pragma unroll
        for (int j = 0; j < 8; ++j) {
            float wv = sc[48+j*16+0];
            float d0 = __fmul_rn(wv, h00[0]);
            float d1 = __fmul_rn(wv, h01[0]);
            float d2 = __fmul_rn(wv, h02[0]);
            #pragma unroll
            for (int o = 1; o < 16; ++o) {
                float wo = sc[48+j*16+o];
                d0 = __builtin_fmaf(wo, h00[o], d0);
                d1 = __builtin_fmaf(wo, h01[o], d1);
                d2 = __builtin_fmaf(wo, h02[o], d2);
            }
            float g1v = sc[176+j], b1v = sc[184+j], w2v = sc[192+j];
            float h10 = fmaxf(__builtin_fmaf(d0, g1v, b1v), 0.f);
            float h11 = fmaxf(__builtin_fmaf(d1, g1v, b1v), 0.f);
            float h12 = fmaxf(__builtin_fmaf(d2, g1v, b1v), 0.f);
            if (j == 0) {
                A0 = __fmul_rn(w2v, h10);
                A1 = __fmul_rn(w2v, h11);
                A2 = __fmul_rn(w2v, h12);
            } else {
                A0 = __builtin_fmaf(w2v, h10, A0);
                A1 = __builtin_fmaf(w2v, h11, A1);
                A2 = __builtin_fmaf(w2v, h12, A2);
            }
        }
        hmax = fmaxf(hmax, __fadd_rn(A0, bb));
        hmax = fmaxf(hmax, __fadd_rn(A1, bb));
        hmax = fmaxf(hmax, __fadd_rn(A2, bb));
    }
    // tree-max within the 8-lane sub-group (groups 8-aligned inside a wave)
    hmax = fmaxf(hmax, __shfl_xor(hmax, 1, 64));
    hmax = fmaxf(hmax, __shfl_xor(hmax, 2, 64));
    hmax = fmaxf(hmax, __shfl_xor(hmax, 4, 64));
    if (sub == 0) {
        float vmax = __fdiv_rn(1.f, __fadd_rn(1.f, np_expf(-hmax)));
        vsm[hw_local*2 + i] = vmax;
        vw_out[(b*(V_-1) + i)*HW + hw] = vmax;
    }
    __syncthreads();

    // simil phase: this block's 16 hw x 48 depths, in place over view-0 region.
    #pragma unroll
    for (int e = tid; e < 16*D_; e += 256) {
        int d  = e >> 4;
        int hl = e & 15;
        int hww = hw0 + hl;
        size_t idx0 = ((size_t)(b*D_ + d))*HW + hww;
        float s0 = sim[idx0];
        float s1 = sim[idx0 + (size_t)B_*D_*HW];
        float v0 = vsm[hl*2 + 0];
        float v1 = vsm[hl*2 + 1];
        float num = __fadd_rn(__fmul_rn(s0, v0), __fmul_rn(s1, v1));
        float den = __fadd_rn(__fadd_rn(1e-5f, v0), v1);
        sim[idx0] = __fdiv_rn(num, den);
    }
}

// conv: 4 outputs along w per thread; 3x3x6 neighborhood preloaded with
// OOB->0 (additive identity == exact tap skip). Per-output tap chain in the
// identical (kd,kh,kw) ascending order -> bit-exact.
__global__ __launch_bounds__(256) void conv_kernel(const float* __restrict__ simil,
                                                   const float* __restrict__ reg_w,
                                                   const float* __restrict__ reg_b,
                                                   float* __restrict__ cost32,
                                                   double* __restrict__ cost64)
{
    __shared__ float srw[27];
    __shared__ double srwd[27];
    int tid = threadIdx.x;
    if (tid < 27) { float v = reg_w[tid]; srw[tid] = v; srwd[tid] = (double)v; }
    __syncthreads();

    int idx = blockIdx.x * 256 + tid;
    if (idx >= B_*D_*H_*(W_/4)) return;
    int w4 = idx % (W_/4);
    int t = idx / (W_/4);
    int h = t % H_;
    t /= H_;
    int d = t % D_;
    int b = t / D_;
    int w0 = w4 * 4;

    const float* sb = simil + (size_t)b*D_*HW;

    // preload 3(z) x 3(y) x 6(x); invalid taps -> 0
    float sv[3][3][6];
    #pragma unroll
    for (int kd = 0; kd < 3; ++kd) {
        int z = d + kd - 1;
        bool vz = (z >= 0) && (z < D_);
        int zc = vz ? z : 0;
        #pragma unroll
        for (int kh = 0; kh < 3; ++kh) {
            int y = h + kh - 1;
            bool vy = (y >= 0) && (y < H_);
            int yc = vy ? y : 0;
            const float* row = sb + ((size_t)zc*H_ + yc)*W_;
            #pragma unroll
            for (int xx = 0; xx < 6; ++xx) {
                int x = w0 + xx - 1;
                bool vx = (x >= 0) && (x < W_);
                int xc = vx ? x : 0;
                float v = row[xc];
                sv[kd][kh][xx] = (vz && vy && vx) ? v : 0.f;
            }
        }
    }

    float a32[4];
    double a64[4];
    #pragma unroll
    for (int o = 0; o < 4; ++o) { a32[o] = 0.f; a64[o] = 0.0; }

    #pragma unroll
    for (int kd = 0; kd < 3; ++kd)
        #pragma unroll
        for (int kh = 0; kh < 3; ++kh)
            #pragma unroll
            for (int kw = 0; kw < 3; ++kw) {
                float wgt = srw[kd*9 + kh*3 + kw];
                double wgtd = srwd[kd*9 + kh*3 + kw];
                #pragma unroll
                for (int o = 0; o < 4; ++o) {
                    float s = sv[kd][kh][o + kw];
                    a32[o] = __fadd_rn(a32[o], __fmul_rn(wgt, s));
                    a64[o] += wgtd * (double)s;
                }
            }

    float bias = reg_b[0];
    size_t base = ((size_t)(b*D_ + d)*H_ + h)*W_ + w0;
    float4 o32;
    o32.x = __fadd_rn(a32[0], bias);
    o32.y = __fadd_rn(a32[1], bias);
    o32.z = __fadd_rn(a32[2], bias);
    o32.w = __fadd_rn(a32[3], bias);
    *(float4*)(cost32 + base) = o32;
    double2 o64a, o64b;
    o64a.x = a64[0]; o64a.y = a64[1];
    o64b.x = a64[2]; o64b.y = a64[3];
    *(double2*)(cost64 + base) = o64a;
    *(double2*)(cost64 + base + 2) = o64b;
}

// softmax + dual-flag tie handling. ALL loops fully unrolled (static indexing)
// so cost[]/e[] live in VGPRs, not scratch. Arithmetic chains in identical order.
__global__ __launch_bounds__(256) void softmax_kernel(const float* __restrict__ cost32,
                                                      const double* __restrict__ cost64,
                                                      const float* __restrict__ depthv,
                                                      float* __restrict__ out)
{
    int idx = blockIdx.x * 256 + threadIdx.x;
    if (idx >= B_*HW) return;
    int hw = idx % HW;
    int b  = idx / HW;

    const float*  cp  = cost32 + (size_t)b*D_*HW + hw;
    const double* cpd = cost64 + (size_t)b*D_*HW + hw;

    float cost[D_];
    #pragma unroll
    for (int d = 0; d < D_; ++d) cost[d] = cp[(size_t)d*HW];

    float cmax = cost[0];
    #pragma unroll
    for (int d = 1; d < D_; ++d) cmax = fmaxf(cmax, cost[d]);

    float e[D_];
    float sum = 0.f;
    #pragma unroll
    for (int d = 0; d < D_; ++d) {
        e[d] = np_expf(__fsub_rn(cost[d], cmax));
        sum = __fadd_rn(sum, e[d]);
    }

    // fp64 argmax (first max wins, strict >)
    double best64 = -1e300; int am64 = 0;
    #pragma unroll
    for (int d = 0; d < D_; ++d) {
        double cd = cpd[(size_t)d*HW];
        if (cd > best64) { best64 = cd; am64 = d; }
    }

    float* prob = out + 2*B_*HW + (size_t)b*D_*HW + hw;
    float pm = -1.f; int am = 0;
    #pragma unroll
    for (int d = 0; d < D_; ++d) {
        float p = __fdiv_rn(e[d], sum);
        prob[(size_t)d*HW] = p;
        if (p > pm) { pm = p; am = d; }   // first max wins
    }

    int partner = -1;
    int ddA = am64 - am; if (ddA < 0) ddA = -ddA;
    if (ddA >= 1 && ddA <= 2) {
        partner = am64;
    } else {
        int lo = am - 2; if (lo < 0) lo = 0;
        int hi = am + 2; if (hi > D_-1) hi = D_-1;
        float bestr = -1e30f; int r = -1;
        #pragma unroll
        for (int d = 0; d < D_; ++d) {
            bool in = (d >= lo) && (d <= hi) && (d != am);
            if (in && cost[d] > bestr) { bestr = cost[d]; r = d; }
        }
        // bestr == cost[r] by construction (avoids dynamic index -> scratch)
        if (r >= 0 && bestr >= cmax - 3e-5f) partner = r;
    }

    float depth_out;
    if (partner >= 0) {
        float a = depthv[((size_t)(b*D_ + am))*HW + hw];
        float c = depthv[((size_t)(b*D_ + partner))*HW + hw];
        depth_out = 0.5f * (a + c);
    } else {
        depth_out = depthv[((size_t)(b*D_ + am))*HW + hw];
    }

    out[idx]         = depth_out;
    out[B_*HW + idx] = pm;
}

extern "C" void kernel_launch(void* const* d_in, const int* in_sizes, int n_in,
                              void* d_out, int out_size, void* d_ws, size_t ws_size,
                              hipStream_t stream)
{
    const float* features = (const float*)d_in[0];
    const float* projm    = (const float*)d_in[1];
    const float* depthv   = (const float*)d_in[2];
    const float* w0 = (const float*)d_in[3];
    const float* g0 = (const float*)d_in[4];
    const float* b0 = (const float*)d_in[5];
    const float* m0 = (const float*)d_in[6];
    const float* v0 = (const float*)d_in[7];
    const float* w1 = (const float*)d_in[8];
    const float* g1 = (const float*)d_in[9];
    const float* b1 = (const float*)d_in[10];
    const float* m1 = (const float*)d_in[11];
    const float* v1 = (const float*)d_in[12];
    const float* w2 = (const float*)d_in[13];
    const float* b2 = (const float*)d_in[14];
    const float* reg_w = (const float*)d_in[15];
    const float* reg_b = (const float*)d_in[16];

    float* ws     = (float*)d_ws;
    float* cst    = ws + WS_CONST;
    float* sim    = ws + WS_SIM;      // view-0 region becomes simil in place
    float* cost32 = ws + WS_COST32;
    double* cost64 = (double*)(ws + WS_COST64F);
    float* feat_t = ws + WS_COST32;   // aliases cost32: dead before conv writes

    float* out = (float*)d_out;
    float* vw_out = out + 2*B_*HW + B_*D_*HW;   // view_weights (B,2,H,W)

    prep_transpose_kernel<<<(B_*V_*HW)/256 + 1, 256, 0, stream>>>(
        features, feat_t, projm, w0,g0,b0,m0,v0, w1,g1,b1,m1,v1, w2,b2, cst);

    sim_kernel<<<(V_-1)*B_*(D_/DCH)*(HW/256), 256, 0, stream>>>(feat_t, depthv, cst, sim);

    vw_simil_kernel<<<B_*(HW/16), 256, 0, stream>>>(sim, cst, vw_out);

    conv_kernel<<<(B_*D_*H_*(W_/4))/256, 256, 0, stream>>>(sim, reg_w, reg_b, cost32, cost64);

    softmax_kernel<<<(B_*HW)/256, 256, 0, stream>>>(cost32, cost64, depthv, out);
}